// Round 5
// baseline (179.579 us; speedup 1.0000x reference)
//
#include <hip/hip_runtime.h>

// Detection post-process: softmax -> decode -> per-class LAZY NMS -> top-100.
// N=8 images, A=16384 anchors, C=21 classes (class 0 = background).
//
// Budget model (R8-R10 counters): ~41us harness ws-fill + ~12us preprocess + nms +
// topk + gaps. R7 nms = 60.4us = ~147k cy/block with only ~32k VALU-busy: the pole
// is the serial lazy walk (~300-450 pops x ~120cy ballot chain) + refills.
// R10 lesson: in-kernel cross-block coherence (__threadfence) costs buffer_wbl2/inv
// L2 flushes (+23us) -- keep the separate topk dispatch.
// R11: replace the serial walk with KILL-MATRIX + BIT-SCAN:
//   - kmask[i] bit j (j<i) = exact IoU>thr predicate, computed fully parallel
//     (balance-paired rows, broadcast LDS reads, ~23k cy, no stalls)
//   - wave0 scan: accept i iff (kmask[i] & accepted_mask)==0 && !dead-from-prev-chunk;
//     2 candidates per __ballot, prefetch depth 2 (~20-25 cy/pop vs ~120)
//   - TARGET 384->448 (fewer refills), accepted list in LDS (parallel rows write)
//   - sort LDS stages double-buffered: 1 barrier/stage (6 vs 12)
// Exactness invariants (absmax 0.0 since R1):
//   - u64 key = (score_bits<<32)|~idx  => exact (score desc, idx asc) total order
//   - monotone bin(float bits) => bin-threshold selection is a key-order cut
//   - scan accept recurrence == lazy NMS: dead entries never kill (bit j only
//     consulted via accepted_mask); same predicate, same order => same accepts
//   - division-free EXACT IoU predicate:
//     RN_f32(inter/un) > 0.45f  <=>  (double)inter > ((double)0.45f + 2^-26)*(double)un

typedef unsigned long long u64;
typedef unsigned char u8;

#define N_IMG 8
#define A     16384
#define NCLS  21
#define NC    20
#define TOPK  100
#define PROB_THR 0.05f

#define TN     512         // 8 waves (R9: fewer waves exposes LDS latency)
#define NSLOT  32          // scores per thread
#define NBIN   1152        // score-bit bins: (bits>>15)-31385 spans (0.05,1]
#define BINOFF 31385
#define CAPC   512         // chunk capacity (sorted)
#define TARGET 448

#define PHYS(i) ((i) + ((i) >> 4))   // LDS u64 swizzle: breaks power-of-2 strides

#define MIDTHR ((double)0.45f + 0x1p-26)

#define AIDX(t_) ((tid << 2) + (((t_) >> 2) << 11) + ((t_) & 3))

__device__ __forceinline__ u64 pk(float v, int i) {
    return (v > 0.f) ? (((u64)__float_as_uint(v) << 32) | (u64)(unsigned)(~(unsigned)i)) : 0ull;
}
__device__ __forceinline__ float upv(u64 k) { return __uint_as_float((unsigned)(k >> 32)); }
__device__ __forceinline__ int   upi(u64 k) { return (int)(~(unsigned)k); }
__device__ __forceinline__ u64 umx(u64 a, u64 b) { return a > b ? a : b; }
__device__ __forceinline__ u64 umn(u64 a, u64 b) { return a < b ? a : b; }

// bitonic compare-exchange keep-rule for element i at stage (k,j)
__device__ __forceinline__ u64 bsel(u64 mine, u64 other, int i, int k, int j) {
    bool keep_max = ((i & k) == 0) == ((i & j) == 0);
    return keep_max ? umx(mine, other) : umn(mine, other);
}

__device__ __forceinline__ int binOf(float s) {
    int b = (int)(__float_as_uint(s) >> 15) - BINOFF;
    return b < 0 ? 0 : (b > NBIN - 1 ? NBIN - 1 : b);
}

// exact ref predicate: RN(inter/union) > 0.45f
__device__ __forceinline__ bool killp(float4 b, float ab, float4 s, float as_) {
    float lx = fmaxf(s.x, b.x), ly = fmaxf(s.y, b.y);
    float rx = fminf(s.z, b.z), ry = fminf(s.w, b.w);
    float iw = fmaxf(rx - lx, 0.f), ih = fmaxf(ry - ly, 0.f);
    float inter = iw * ih;
    float un = as_ + ab - inter;
    return (double)inter > MIDTHR * (double)un;
}

struct SMem {
    int bins[NBIN];
    u64 skey[2][PHYS(CAPC - 1) + 2];   // double-buffered sort keys
    float4 sbox[CAPC];
    float sarea[CAPC];
    u64 kmask[CAPC][8];                // kill matrix: row i, bit j<i
    u8 sdead[CAPC];                    // killed-by-prev-chunk-accepts
    float4 abox[TOPK];                 // accepted boxes (order of acceptance)
    float aarea[TOPK];
    u64 akey[TOPK];
    int alist[TOPK];                   // chunk-local accepted indices
    u64 red8[TN / 64];
    u64 bkey;
    float4 bbox;
    int sint[4];   // 0:B  1:cnt  2:degenerate  3:naNew
};

// Kernel 1: softmax + threshold -> scores[N][NC][A]; SSD decode -> clamped corner boxes.
__global__ __launch_bounds__(256) void preprocess_kernel(
    const float* __restrict__ cls, const float* __restrict__ reg,
    const float* __restrict__ anc, float4* __restrict__ boxes,
    float* __restrict__ scores) {
    __shared__ __align__(16) float lcls[256 * NCLS];
    const int tid = threadIdx.x;
    const int t = blockIdx.x * 256 + tid;

    const float4* src = (const float4*)(cls + (size_t)blockIdx.x * (256 * NCLS));
    float4* dst = (float4*)lcls;
    for (int i = tid; i < (256 * NCLS) / 4; i += 256) dst[i] = src[i];
    __syncthreads();

    const int n = t >> 14;
    const int a = t & (A - 1);
    const float* c = lcls + tid * NCLS;
    float z[NCLS];
    float m = -1e30f;
#pragma unroll
    for (int k = 0; k < NCLS; ++k) { z[k] = c[k]; m = fmaxf(m, z[k]); }
    float s = 0.f;
#pragma unroll
    for (int k = 0; k < NCLS; ++k) { z[k] = expf(z[k] - m); s += z[k]; }
    const float inv = 1.f / s;
#pragma unroll
    for (int k = 0; k < NC; ++k) {
        float p = z[k + 1] * inv;
        scores[(((size_t)n * NC + k) << 14) + a] = (p > PROB_THR) ? p : -1.f;
    }

    const float4 l4 = ((const float4*)reg)[t];
    const float4 an = ((const float4*)anc)[a];
    const float cx = an.x + l4.x * 0.1f * an.z;
    const float cy = an.y + l4.y * 0.1f * an.w;
    const float w  = an.z * expf(l4.z * 0.2f);
    const float h  = an.w * expf(l4.w * 0.2f);
    float x0 = fminf(fmaxf(cx - 0.5f * w, 0.f), 1.f);
    float y0 = fminf(fmaxf(cy - 0.5f * h, 0.f), 1.f);
    float x1 = fminf(fmaxf(cx + 0.5f * w, 0.f), 1.f);
    float y1 = fminf(fmaxf(cy + 0.5f * h, 0.f), 1.f);
    boxes[t] = make_float4(x0, y0, x1, y1);
}

// Kernel 2: one workgroup per (n, ci). hist-select -> sort-512 -> kill-matrix -> bit-scan.
__global__ __launch_bounds__(TN) void nms_kernel(
    const float4* __restrict__ boxes, const float* __restrict__ scores,
    float* __restrict__ rows) {
    __shared__ SMem sm;

    const int blk = blockIdx.x, n = blk / NC, ci = blk % NC;
    const int tid = threadIdx.x, lane = tid & 63, w = tid >> 6;
    const float* gs = scores + ((size_t)blk << 14);
    const float4* gb = boxes + ((size_t)n << 14);
    float* grows = rows + (size_t)blk * 600;

    // scores -> registers (coalesced float4)
    float sc[NSLOT];
    const float4* gs4 = (const float4*)gs;
#pragma unroll
    for (int k = 0; k < NSLOT / 4; ++k) {
        float4 v = gs4[tid + (k << 9)];
        sc[k * 4 + 0] = v.x; sc[k * 4 + 1] = v.y; sc[k * 4 + 2] = v.z; sc[k * 4 + 3] = v.w;
    }

    int na = 0;
    u64 filter = ~0ull;
    bool done = false;

    while (!done && na < TOPK) {
        // ---- filtered histogram ----
        for (int i = tid; i < NBIN; i += TN) sm.bins[i] = 0;
        if (tid == 0) { sm.sint[1] = 0; sm.sint[2] = 0; }
        __syncthreads();
#pragma unroll
        for (int t = 0; t < NSLOT; ++t) {
            float s = sc[t];
            if (s > 0.f) {
                u64 kk = pk(s, AIDX(t));
                if (kk < filter) atomicAdd(&sm.bins[binOf(s)], 1);
            }
        }
        __syncthreads();

        // ---- select bin threshold B (wave0) ----
        if (tid < 64) {
            int lsum[18];
            int tot = 0;
#pragma unroll
            for (int k = 0; k < 18; ++k) { lsum[k] = sm.bins[tid * 18 + k]; tot += lsum[k]; }
            int pfx = tot;
#pragma unroll
            for (int off = 1; off < 64; off <<= 1) {
                int o = __shfl_up(pfx, off, 64);
                if (lane >= off) pfx += o;
            }
            const int totalAll = __shfl(pfx, 63, 64);
            const int sufAbove = totalAll - pfx;
            const int tgt = totalAll < TARGET ? totalAll : TARGET;
            int run = 0, b1 = -1, b2 = 1 << 30;
#pragma unroll
            for (int k = 17; k >= 0; --k) {
                run += lsum[k];
                int suf = sufAbove + run;
                int b = tid * 18 + k;
                if (suf >= tgt && b > b1) b1 = b;
                if (suf <= CAPC && b < b2) b2 = b;
            }
#pragma unroll
            for (int off = 1; off < 64; off <<= 1) {
                int o1 = __shfl_xor(b1, off, 64); if (o1 > b1) b1 = o1;
                int o2 = __shfl_xor(b2, off, 64); if (o2 < b2) b2 = o2;
            }
            if (lane == 0) {
                sm.sint[0] = b1 > b2 ? b1 : b2;
                sm.sint[2] = (b2 == (1 << 30)) ? 1 : 0;
            }
        }
        __syncthreads();
        const int B = sm.sint[0];
        const int degen = sm.sint[2];

        if (degen) {
            // ---- degenerate (one bin > CAPC; never on real data): single extractions ----
            while (na < TOPK) {
                u64 best = 0ull;
#pragma unroll
                for (int t = 0; t < NSLOT; ++t) {
                    float s = sc[t];
                    if (s > 0.f) {
                        u64 kk = pk(s, AIDX(t));
                        if (kk < filter && kk > best) best = kk;
                    }
                }
#pragma unroll
                for (int off = 1; off < 64; off <<= 1) best = umx(best, __shfl_xor(best, off, 64));
                if (lane == 0) sm.red8[w] = best;
                __syncthreads();
                if (tid == 0) {
                    u64 bb = sm.red8[0];
#pragma unroll
                    for (int q = 1; q < TN / 64; ++q) bb = umx(bb, sm.red8[q]);
                    sm.bkey = bb;
                    if (bb) sm.bbox = gb[upi(bb)];
                }
                __syncthreads();
                u64 kk = sm.bkey;
                if (!kk) break;
                filter = kk;
                float4 cb = sm.bbox;
                float ca = (cb.z - cb.x) * (cb.w - cb.y);
                bool kill = false;
                if (lane < na)      kill = killp(cb, ca, sm.abox[lane], sm.aarea[lane]);
                if (lane + 64 < na) kill = kill || killp(cb, ca, sm.abox[lane + 64], sm.aarea[lane + 64]);
                if (!__any(kill)) {
                    if (tid == 0) { sm.abox[na] = cb; sm.aarea[na] = ca; sm.akey[na] = kk; }
                    ++na;           // uniform (all waves agree: same data, same math)
                }
                __syncthreads();
            }
            break;
        }

        // ---- compact keys of bins >= B into skey[0] ----
#pragma unroll
        for (int t = 0; t < NSLOT; ++t) {
            float s = sc[t];
            bool pred = false; u64 kk = 0ull;
            if (s > 0.f && binOf(s) >= B) {
                kk = pk(s, AIDX(t));
                pred = (kk < filter);
            }
            u64 m = __ballot(pred);
            if (m) {
                int bse = 0;
                if (lane == 0) bse = atomicAdd(&sm.sint[1], __popcll(m));
                bse = __shfl(bse, 0, 64);
                if (pred) {
                    int sl = bse + __popcll(m & ((1ull << lane) - 1ull));
                    sm.skey[0][PHYS(sl)] = kk;
                }
            }
        }
        __syncthreads();
        const int T = sm.sint[1];
        if (T == 0) break;                       // exhausted
        for (int i = T + tid; i < CAPC; i += TN) sm.skey[0][PHYS(i)] = 0ull;
        __syncthreads();

        // ---- hybrid bitonic sort-512 desc: shfl j<=32; LDS j>=64 double-buffered
        // (1 barrier/stage: stage s writes the buffer whose last cross-reads were
        //  two stages back, separated by the intervening barrier -> race-free) ----
        u64* wb = sm.skey[1];
        {
            u64 myk = sm.skey[0][PHYS(tid)];
            for (int kk2 = 2; kk2 <= CAPC; kk2 <<= 1) {
                for (int j = kk2 >> 1; j > 0; j >>= 1) {
                    u64 other;
                    if (j >= 64) {
                        wb[PHYS(tid)] = myk;
                        __syncthreads();
                        other = wb[PHYS(tid ^ j)];
                        wb = (wb == sm.skey[1]) ? sm.skey[0] : sm.skey[1];
                    } else {
                        other = __shfl_xor(myk, j, 64);
                    }
                    myk = bsel(myk, other, tid, kk2, j);
                }
            }
            wb[PHYS(tid)] = myk;   // 6 LDS stages -> wb back to skey[1]; its last
        }                          // cross-reads preceded the stage-6 barrier: safe
        __syncthreads();
        u64* skf = wb;             // == sm.skey[1]

        // ---- gather candidate boxes + areas in sorted order ----
        for (int p = tid; p < CAPC; p += TN) {
            u64 kk = skf[PHYS(p)];
            if (kk) {
                float4 b = gb[upi(kk)];
                sm.sbox[p] = b;
                sm.sarea[p] = (b.z - b.x) * (b.w - b.y);
            }
        }
        const bool havePrev = (na > 0);
        __syncthreads();

        // ---- kill matrix: thread t<256 computes rows t and 511-t (balanced:
        // t + (511-t) = 511 iters/thread), broadcast reads of sbox[j] ----
        if (tid < CAPC / 2) {
            const int r1 = tid;
            if (r1 < T && r1 > 0) {
                float4 cb = sm.sbox[r1]; float ca = sm.sarea[r1];
                u64 wacc = 0ull;
                for (int j = 0; j < r1; ++j) {
                    bool kp = killp(cb, ca, sm.sbox[j], sm.sarea[j]);
                    wacc |= ((u64)kp) << (j & 63);
                    if ((j & 63) == 63) { sm.kmask[r1][j >> 6] = wacc; wacc = 0ull; }
                }
                if (r1 & 63) sm.kmask[r1][r1 >> 6] = wacc;
            }
            const int r2 = CAPC - 1 - tid;
            if (r2 < T) {
                float4 cb = sm.sbox[r2]; float ca = sm.sarea[r2];
                u64 wacc = 0ull;
                for (int j = 0; j < r2; ++j) {
                    bool kp = killp(cb, ca, sm.sbox[j], sm.sarea[j]);
                    wacc |= ((u64)kp) << (j & 63);
                    if ((j & 63) == 63) { sm.kmask[r2][j >> 6] = wacc; wacc = 0ull; }
                }
                if (r2 & 63) sm.kmask[r2][r2 >> 6] = wacc;
            }
        }
        if (tid == 0) sm.kmask[0][0] = 0ull;   // row 0 has no predecessors
        // ---- prev-chunk dead column (refills only) ----
        if (havePrev && tid < T) {
            float4 cb = sm.sbox[tid]; float ca = sm.sarea[tid];
            bool d = false;
            for (int q = 0; q < na; ++q)
                d = d || killp(cb, ca, sm.abox[q], sm.aarea[q]);
            sm.sdead[tid] = d ? 1 : 0;
        }
        __syncthreads();

        // ---- bit-scan (wave0): 2 candidates per ballot, prefetch depth 2 ----
        if (w == 0) {
            const int rw = lane & 7;
            int naL = na;
            u64 acc = 0ull;            // per-lane copy of accepted-mask word (lane&7)
            bool fin = false;
            int i = 0;
            u64 cwA = sm.kmask[0][rw];
            u64 cwB = 0ull; u8 cd0 = 0, cd1 = 0;
            if (havePrev) cd0 = sm.sdead[0];
            if (1 < T) {
                cwB = sm.kmask[1][(lane == 16) ? 0 : rw];
                if (havePrev) cd1 = sm.sdead[1];
            }
            while (i < T && !fin) {
                const bool hasB = (i + 1 < T);
                const int i2 = i + 2;
                u64 nwA = 0ull, nwB = 0ull; u8 nd0 = 0, nd1 = 0;
                if (i2 < T) {
                    nwA = sm.kmask[i2][rw];
                    if (havePrev) nd0 = sm.sdead[i2];
                    if (i2 + 1 < T) {
                        nwB = sm.kmask[i2 + 1][(lane == 16) ? (i2 >> 6) : rw];
                        if (havePrev) nd1 = sm.sdead[i2 + 1];
                    }
                }
                bool pred;
                if (lane < 8)        pred = (cwA & acc) != 0ull;
                else if (lane < 16)  pred = (cwB & acc) != 0ull;
                else if (lane == 16) pred = ((cwB >> (i & 63)) & 1ull) != 0ull;
                else if (lane == 17) pred = (cd0 != 0);
                else if (lane == 18) pred = (cd1 != 0);
                else                 pred = false;
                u64 m = __ballot(pred);
                bool a0 = ((m & 0xFFull) == 0ull) && (((m >> 17) & 1ull) == 0ull);
                if (a0) { if (lane == 0) sm.alist[naL] = i; }
                int naM = naL + (a0 ? 1 : 0);
                bool killB = (((m >> 8) & 0xFFull) != 0ull) ||
                             (((m >> 18) & 1ull) != 0ull) ||
                             (a0 && (((m >> 16) & 1ull) != 0ull));
                bool a1 = hasB && !killB && (naM < TOPK);
                if (a1) { if (lane == 0) sm.alist[naM] = i + 1; }
                if (a0 && ((i >> 6) == rw))       acc |= 1ull << (i & 63);
                if (a1 && (((i + 1) >> 6) == rw)) acc |= 1ull << ((i + 1) & 63);
                naL = naM + (a1 ? 1 : 0);
                fin = (naL >= TOPK);
                cwA = nwA; cwB = nwB; cd0 = nd0; cd1 = nd1;
                i = i2;
            }
            if (lane == 0) sm.sint[3] = naL;
        }
        __syncthreads();

        // ---- commit accepts (parallel) ----
        const int naNew = sm.sint[3];
        if (tid >= na && tid < naNew) {
            int i = sm.alist[tid];
            sm.abox[tid] = sm.sbox[i];
            sm.aarea[tid] = sm.sarea[i];
            sm.akey[tid] = skf[PHYS(i)];
        }
        done = (naNew >= TOPK);
        if (!done) filter = skf[PHYS(T - 1)];   // chunk exhausted: next keys < min key
        na = naNew;
        __syncthreads();                        // abox/akey visible before reuse
    }

    // ---- final rows write (parallel, from accepted list) ----
    if (tid < na) {
        float4 b = sm.abox[tid];
        u64 kk = sm.akey[tid];
        float* o = grows + tid * 6;
        o[0] = b.x; o[1] = b.y; o[2] = b.z; o[3] = b.w;
        o[4] = upv(kk); o[5] = (float)(ci + 1);
    }
    for (int j = na * 6 + tid; j < 600; j += TN) grows[j] = 0.f;
}

// Kernel 3: per image, bitonic sort of all 2048 padded candidate keys, gather top-100.
// key = (score_bits<<32) | (0xFFFFFFFF - flat_j), flat_j = (ci+1)*100 + pos. Exact
// lax.top_k order; zero-score selections are all-zero rows in both ref and ours.
// Hybrid shuffle/LDS bitonic, 2 keys/thread; only j>=128 via LDS.
__global__ __launch_bounds__(1024) void topk_kernel(
    const float* __restrict__ rows, float* __restrict__ out) {
    __shared__ u64 skey[PHYS(2047) + 2];
    const int n = blockIdx.x, tid = threadIdx.x;
    const float* base = rows + (size_t)n * (NC * 600);
    const int i0 = tid << 1, i1 = i0 | 1;

    u64 k0 = 0ull, k1 = 0ull;
    if (i0 < 2000) {
        int ci = i0 / 100, pos = i0 - ci * 100;
        float s = base[ci * 600 + pos * 6 + 4];
        k0 = ((u64)__float_as_uint(s) << 32) | (u64)(0xFFFFFFFFu - (unsigned)(i0 + 100));
    }
    if (i1 < 2000) {
        int ci = i1 / 100, pos = i1 - ci * 100;
        float s = base[ci * 600 + pos * 6 + 4];
        k1 = ((u64)__float_as_uint(s) << 32) | (u64)(0xFFFFFFFFu - (unsigned)(i1 + 100));
    }

    for (int kk2 = 2; kk2 <= 2048; kk2 <<= 1) {
        for (int j = kk2 >> 1; j > 0; j >>= 1) {
            if (j >= 128) {
                skey[PHYS(i0)] = k0; skey[PHYS(i1)] = k1;
                __syncthreads();
                u64 o0 = skey[PHYS(i0 ^ j)], o1 = skey[PHYS(i1 ^ j)];
                __syncthreads();
                k0 = bsel(k0, o0, i0, kk2, j);
                k1 = bsel(k1, o1, i1, kk2, j);
            } else if (j >= 2) {
                u64 o0 = __shfl_xor(k0, j >> 1, 64);
                u64 o1 = __shfl_xor(k1, j >> 1, 64);
                k0 = bsel(k0, o0, i0, kk2, j);
                k1 = bsel(k1, o1, i1, kk2, j);
            } else {
                bool mx0 = ((i0 & kk2) == 0);
                u64 mx = umx(k0, k1), mn = umn(k0, k1);
                k0 = mx0 ? mx : mn; k1 = mx0 ? mn : mx;
            }
        }
    }
    skey[PHYS(i0)] = k0; skey[PHYS(i1)] = k1;   // last cross-wave read was pre-barrier
    __syncthreads();

    if (tid < 600) {
        int r = tid / 6, f = tid - (tid / 6) * 6;
        u64 kk = skey[PHYS(r)];
        float v = 0.f;
        if ((unsigned)(kk >> 32) != 0u) {
            int e = (int)(0xFFFFFFFFu - (unsigned)kk) - 100;
            int ci = e / 100, pos = e - ci * 100;
            v = base[ci * 600 + pos * 6 + f];
        }
        out[(size_t)n * 600 + tid] = v;
    }
}

extern "C" void kernel_launch(void* const* d_in, const int* in_sizes, int n_in,
                              void* d_out, int out_size, void* d_ws, size_t ws_size,
                              hipStream_t stream) {
    const float* cls = (const float*)d_in[0];   // [8,16384,21]
    const float* reg = (const float*)d_in[1];   // [8,16384,4]
    const float* anc = (const float*)d_in[2];   // [16384,4]
    float* out = (float*)d_out;                 // [8,100,6]

    // ws layout (floats): boxes 524288 | scores 2621440 | rows 96000
    float* boxes  = (float*)d_ws;
    float* scores = boxes + (size_t)N_IMG * A * 4;
    float* rows   = scores + (size_t)N_IMG * NC * A;

    preprocess_kernel<<<(N_IMG * A) / 256, 256, 0, stream>>>(cls, reg, anc, (float4*)boxes, scores);
    nms_kernel<<<N_IMG * NC, TN, 0, stream>>>((const float4*)boxes, scores, rows);
    topk_kernel<<<N_IMG, 1024, 0, stream>>>(rows, out);
}

// Round 6
// 154.658 us; speedup vs baseline: 1.1611x; 1.1611x over previous
//
#include <hip/hip_runtime.h>

// Detection post-process: softmax -> decode -> per-class LAZY NMS -> top-100.
// N=8 images, A=16384 anchors, C=21 classes (class 0 = background).
//
// Budget model (R8-R11 counters): ~41us harness ws-fill (fixed) + ~12us preprocess
// + nms + ~15us topk + gaps. R7 nms = 60.4us @ TN=512.
// R9: TN 512->256 gave EXACTLY 2x nms (121.6us) => the body is issue/throughput-
// bound in its parallel phases (load/hist/compact/sort/gather), NOT walk-latency-
// bound. R11 (kill-matrix, 100k pair-IoUs) regressed to 96us -- reverted.
// R10: in-kernel cross-block coherence costs buffer_wbl2/inv (+23us) -- topk stays
// a separate dispatch.
// R12: exploit the measured scaling law upward: TN 512->1024 (16 waves, 4/SIMD),
// NSLOT 32->16. R7 body otherwise byte-identical; sort-512 runs on tid<512 (same
// network). Predict nms ~35-42us if time ~ 1/threads holds.
// Exactness invariants (absmax 0.0 since R1):
//   - u64 key = (score_bits<<32)|~idx  => exact (score desc, idx asc) total order
//   - monotone bin(float bits) => bin-threshold selection is a key-order cut
//   - lazy NMS: dead entries never kill => test pops against accepted set only
//   - division-free EXACT IoU predicate:
//     RN_f32(inter/un) > 0.45f  <=>  (double)inter > ((double)0.45f + 2^-26)*(double)un
//   - topk key = (score_bits<<32)|(0xFFFFFFFF-(flat_j+100)) => exact lax.top_k order

typedef unsigned long long u64;

#define N_IMG 8
#define A     16384
#define NCLS  21
#define NC    20
#define TOPK  100
#define PROB_THR 0.05f

#define TN     1024        // nms threads (16 waves, 4/SIMD). R9: halving doubled time.
#define NSLOT  16          // scores per thread
#define NBIN   1152        // score-bit bins: (bits>>15)-31385 spans (0.05,1]
#define BINOFF 31385
#define CAPC   512         // chunk capacity (sorted); expected pops ~150-250
#define TARGET 384

#define PHYS(i) ((i) + ((i) >> 4))   // LDS u64 swizzle: breaks power-of-2 strides

#define MIDTHR ((double)0.45f + 0x1p-26)

// anchor index for slot t of thread tid (float4 load pattern, TN=1024)
#define AIDX(t_) ((tid << 2) + (((t_) >> 2) << 12) + ((t_) & 3))

__device__ __forceinline__ u64 pk(float v, int i) {
    return (v > 0.f) ? (((u64)__float_as_uint(v) << 32) | (u64)(unsigned)(~(unsigned)i)) : 0ull;
}
__device__ __forceinline__ float upv(u64 k) { return __uint_as_float((unsigned)(k >> 32)); }
__device__ __forceinline__ int   upi(u64 k) { return (int)(~(unsigned)k); }
__device__ __forceinline__ u64 umx(u64 a, u64 b) { return a > b ? a : b; }
__device__ __forceinline__ u64 umn(u64 a, u64 b) { return a < b ? a : b; }

// bitonic compare-exchange keep-rule for element i at stage (k,j):
// region (i&k)==0 sorts descending; lower partner ((i&j)==0) keeps max there.
__device__ __forceinline__ u64 bsel(u64 mine, u64 other, int i, int k, int j) {
    bool keep_max = ((i & k) == 0) == ((i & j) == 0);
    return keep_max ? umx(mine, other) : umn(mine, other);
}

__device__ __forceinline__ int binOf(float s) {
    int b = (int)(__float_as_uint(s) >> 15) - BINOFF;
    return b < 0 ? 0 : (b > NBIN - 1 ? NBIN - 1 : b);
}

// exact ref predicate: RN(inter/union) > 0.45f
__device__ __forceinline__ bool killp(float4 b, float ab, float4 s, float as_) {
    float lx = fmaxf(s.x, b.x), ly = fmaxf(s.y, b.y);
    float rx = fminf(s.z, b.z), ry = fminf(s.w, b.w);
    float iw = fmaxf(rx - lx, 0.f), ih = fmaxf(ry - ly, 0.f);
    float inter = iw * ih;
    float un = as_ + ab - inter;
    return (double)inter > MIDTHR * (double)un;
}

// Kernel 1: softmax + threshold -> scores[N][NC][A]; SSD decode -> clamped corner boxes.
__global__ __launch_bounds__(256) void preprocess_kernel(
    const float* __restrict__ cls, const float* __restrict__ reg,
    const float* __restrict__ anc, float4* __restrict__ boxes,
    float* __restrict__ scores) {
    __shared__ __align__(16) float lcls[256 * NCLS];
    const int tid = threadIdx.x;
    const int t = blockIdx.x * 256 + tid;

    const float4* src = (const float4*)(cls + (size_t)blockIdx.x * (256 * NCLS));
    float4* dst = (float4*)lcls;
    for (int i = tid; i < (256 * NCLS) / 4; i += 256) dst[i] = src[i];
    __syncthreads();

    const int n = t >> 14;
    const int a = t & (A - 1);
    const float* c = lcls + tid * NCLS;
    float z[NCLS];
    float m = -1e30f;
#pragma unroll
    for (int k = 0; k < NCLS; ++k) { z[k] = c[k]; m = fmaxf(m, z[k]); }
    float s = 0.f;
#pragma unroll
    for (int k = 0; k < NCLS; ++k) { z[k] = expf(z[k] - m); s += z[k]; }
    const float inv = 1.f / s;
#pragma unroll
    for (int k = 0; k < NC; ++k) {
        float p = z[k + 1] * inv;
        scores[(((size_t)n * NC + k) << 14) + a] = (p > PROB_THR) ? p : -1.f;
    }

    const float4 l4 = ((const float4*)reg)[t];
    const float4 an = ((const float4*)anc)[a];
    const float cx = an.x + l4.x * 0.1f * an.z;
    const float cy = an.y + l4.y * 0.1f * an.w;
    const float w  = an.z * expf(l4.z * 0.2f);
    const float h  = an.w * expf(l4.w * 0.2f);
    float x0 = fminf(fmaxf(cx - 0.5f * w, 0.f), 1.f);
    float y0 = fminf(fmaxf(cy - 0.5f * h, 0.f), 1.f);
    float x1 = fminf(fmaxf(cx + 0.5f * w, 0.f), 1.f);
    float y1 = fminf(fmaxf(cy + 0.5f * h, 0.f), 1.f);
    boxes[t] = make_float4(x0, y0, x1, y1);
}

// Kernel 2: one workgroup per (n, ci). Histogram-select -> sort-512 -> lazy walk.
__global__ __launch_bounds__(TN) void nms_kernel(
    const float4* __restrict__ boxes, const float* __restrict__ scores,
    float* __restrict__ rows) {
    __shared__ int bins[NBIN];
    __shared__ u64 skey[PHYS(CAPC - 1) + 2];
    __shared__ __align__(16) float4 sbox[CAPC];
    __shared__ u64 red8[TN / 64];
    __shared__ u64 bkey;
    __shared__ __align__(16) float4 bbox;
    __shared__ int sint[3];   // 0:B  1:cnt  2:degenerate

    const int blk = blockIdx.x, n = blk / NC, ci = blk % NC;
    const int tid = threadIdx.x, lane = tid & 63, w = tid >> 6;
    const float* gs = scores + ((size_t)blk << 14);
    const float4* gb = boxes + ((size_t)n << 14);
    float* grows = rows + (size_t)blk * 600;

    // scores -> registers (coalesced float4)
    float sc[NSLOT];
    const float4* gs4 = (const float4*)gs;
#pragma unroll
    for (int k = 0; k < NSLOT / 4; ++k) {
        float4 v = gs4[tid + (k << 10)];
        sc[k * 4 + 0] = v.x; sc[k * 4 + 1] = v.y; sc[k * 4 + 2] = v.z; sc[k * 4 + 3] = v.w;
    }

    float4 accA, accB;
    float arA = 0.f, arB = 0.f;
    int na = 0;
    u64 filter = ~0ull;
    bool done = false;

    while (!done && na < TOPK) {
        // ---- filtered histogram ----
        for (int i = tid; i < NBIN; i += TN) bins[i] = 0;
        if (tid == 0) { sint[1] = 0; sint[2] = 0; }
        __syncthreads();
#pragma unroll
        for (int t = 0; t < NSLOT; ++t) {
            float s = sc[t];
            if (s > 0.f) {
                u64 kk = pk(s, AIDX(t));
                if (kk < filter) atomicAdd(&bins[binOf(s)], 1);
            }
        }
        __syncthreads();

        // ---- select bin threshold B (wave0) ----
        if (tid < 64) {
            int lsum[18];
            int tot = 0;
#pragma unroll
            for (int k = 0; k < 18; ++k) { lsum[k] = bins[tid * 18 + k]; tot += lsum[k]; }
            int pfx = tot;
#pragma unroll
            for (int off = 1; off < 64; off <<= 1) {
                int o = __shfl_up(pfx, off, 64);
                if (lane >= off) pfx += o;
            }
            const int totalAll = __shfl(pfx, 63, 64);
            const int sufAbove = totalAll - pfx;
            const int tgt = totalAll < TARGET ? totalAll : TARGET;
            int run = 0, b1 = -1, b2 = 1 << 30;
#pragma unroll
            for (int k = 17; k >= 0; --k) {
                run += lsum[k];
                int suf = sufAbove + run;
                int b = tid * 18 + k;
                if (suf >= tgt && b > b1) b1 = b;
                if (suf <= CAPC && b < b2) b2 = b;
            }
#pragma unroll
            for (int off = 1; off < 64; off <<= 1) {
                int o1 = __shfl_xor(b1, off, 64); if (o1 > b1) b1 = o1;
                int o2 = __shfl_xor(b2, off, 64); if (o2 < b2) b2 = o2;
            }
            if (lane == 0) {
                sint[0] = b1 > b2 ? b1 : b2;
                sint[2] = (b2 == (1 << 30)) ? 1 : 0;
            }
        }
        __syncthreads();
        const int B = sint[0];
        const int degen = sint[2];

        if (!degen) {
            // ---- compact keys of bins >= B (ballot-aggregated; order fixed by sort) ----
#pragma unroll
            for (int t = 0; t < NSLOT; ++t) {
                float s = sc[t];
                bool pred = false; u64 kk = 0ull;
                if (s > 0.f && binOf(s) >= B) {
                    kk = pk(s, AIDX(t));
                    pred = (kk < filter);
                }
                u64 m = __ballot(pred);
                if (m) {
                    int bse = 0;
                    if (lane == 0) bse = atomicAdd(&sint[1], __popcll(m));
                    bse = __shfl(bse, 0, 64);
                    if (pred) {
                        int sl = bse + __popcll(m & ((1ull << lane) - 1ull));
                        skey[PHYS(sl)] = kk;
                    }
                }
            }
            __syncthreads();
            const int T = sint[1];
            if (T == 0) break;                       // exhausted
            for (int i = T + tid; i < CAPC; i += TN) skey[PHYS(i)] = 0ull;
            __syncthreads();

            // ---- hybrid bitonic sort 512 u64 desc on tid<512: __shfl_xor j<=32,
            // LDS j>=64. Threads >=512 idle through (barriers unconditional). ----
            {
                const bool act = (tid < CAPC);
                u64 myk = act ? skey[PHYS(tid)] : 0ull;
                for (int kk2 = 2; kk2 <= CAPC; kk2 <<= 1) {
                    for (int j = kk2 >> 1; j > 0; j >>= 1) {
                        if (j >= 64) {
                            if (act) skey[PHYS(tid)] = myk;
                            __syncthreads();
                            u64 other = act ? skey[PHYS(tid ^ j)] : 0ull;
                            __syncthreads();
                            if (act) myk = bsel(myk, other, tid, kk2, j);
                        } else {
                            u64 other = __shfl_xor(myk, j, 64);
                            if (act) myk = bsel(myk, other, tid, kk2, j);
                        }
                    }
                }
                if (act) skey[PHYS(tid)] = myk;   // last cross-read was pre-barrier: safe
            }
            __syncthreads();

            // ---- prefetch candidate boxes in sorted order ----
            for (int p = tid; p < CAPC; p += TN) {
                u64 kk = skey[PHYS(p)];
                if (kk) sbox[p] = gb[upi(kk)];
            }
            __syncthreads();

            // ---- lazy walk (all waves redundantly; +1-deep register prefetch) ----
            u64 nk = skey[PHYS(0)];
            float4 nb = sbox[0];
            for (int p = 0; p < T; ++p) {
                u64 kk = nk; float4 cb = nb;
                if (p + 1 < T) { nk = skey[PHYS(p + 1)]; nb = sbox[p + 1]; }
                filter = kk;
                float ca = (cb.z - cb.x) * (cb.w - cb.y);
                bool kill = false;
                if (lane < na)      kill = killp(cb, ca, accA, arA);
                if (lane + 64 < na) kill = kill || killp(cb, ca, accB, arB);
                if (!__any(kill)) {
                    if (tid == 0) {
                        float* o = grows + na * 6;
                        o[0] = cb.x; o[1] = cb.y; o[2] = cb.z; o[3] = cb.w;
                        o[4] = upv(kk); o[5] = (float)(ci + 1);
                    }
                    if (na < 64) { if (lane == na) { accA = cb; arA = ca; } }
                    else if (lane == na - 64) { accB = cb; arB = ca; }
                    ++na;
                    if (na == TOPK) { done = true; break; }
                }
            }
            // next refill's LDS writes are gated by two barriers before any store,
            // so no race with waves still finishing this walk.
        } else {
            // ---- degenerate (one bin > CAPC; never on real data): single extractions ----
            while (na < TOPK) {
                u64 best = 0ull;
#pragma unroll
                for (int t = 0; t < NSLOT; ++t) {
                    float s = sc[t];
                    if (s > 0.f) {
                        u64 kk = pk(s, AIDX(t));
                        if (kk < filter && kk > best) best = kk;
                    }
                }
#pragma unroll
                for (int off = 1; off < 64; off <<= 1) best = umx(best, __shfl_xor(best, off, 64));
                if (lane == 0) red8[w] = best;
                __syncthreads();
                if (tid == 0) {
                    u64 bb = red8[0];
#pragma unroll
                    for (int q = 1; q < TN / 64; ++q) bb = umx(bb, red8[q]);
                    bkey = bb;
                    if (bb) bbox = gb[upi(bb)];
                }
                __syncthreads();
                u64 kk = bkey;
                if (!kk) break;
                filter = kk;
                float4 cb = bbox;
                float ca = (cb.z - cb.x) * (cb.w - cb.y);
                bool kill = false;
                if (lane < na)      kill = killp(cb, ca, accA, arA);
                if (lane + 64 < na) kill = kill || killp(cb, ca, accB, arB);
                if (!__any(kill)) {
                    if (tid == 0) {
                        float* o = grows + na * 6;
                        o[0] = cb.x; o[1] = cb.y; o[2] = cb.z; o[3] = cb.w;
                        o[4] = upv(kk); o[5] = (float)(ci + 1);
                    }
                    if (na < 64) { if (lane == na) { accA = cb; arA = ca; } }
                    else if (lane == na - 64) { accB = cb; arB = ca; }
                    ++na;
                }
                __syncthreads();
            }
            break;
        }
    }
    for (int j = na * 6 + tid; j < 600; j += TN) grows[j] = 0.f;
}

// Kernel 3: per image, bitonic sort of all 2048 padded candidate keys, gather top-100.
// key = (score_bits<<32) | (0xFFFFFFFF - flat_j), flat_j = (ci+1)*100 + pos. Exact
// lax.top_k order; zero-score selections are all-zero rows in both ref and ours.
// Hybrid shuffle/LDS bitonic, 2 keys/thread; only j>=128 via LDS.
__global__ __launch_bounds__(1024) void topk_kernel(
    const float* __restrict__ rows, float* __restrict__ out) {
    __shared__ u64 skey[PHYS(2047) + 2];
    const int n = blockIdx.x, tid = threadIdx.x;
    const float* base = rows + (size_t)n * (NC * 600);
    const int i0 = tid << 1, i1 = i0 | 1;

    u64 k0 = 0ull, k1 = 0ull;
    if (i0 < 2000) {
        int ci = i0 / 100, pos = i0 - ci * 100;
        float s = base[ci * 600 + pos * 6 + 4];
        k0 = ((u64)__float_as_uint(s) << 32) | (u64)(0xFFFFFFFFu - (unsigned)(i0 + 100));
    }
    if (i1 < 2000) {
        int ci = i1 / 100, pos = i1 - ci * 100;
        float s = base[ci * 600 + pos * 6 + 4];
        k1 = ((u64)__float_as_uint(s) << 32) | (u64)(0xFFFFFFFFu - (unsigned)(i1 + 100));
    }

    for (int kk2 = 2; kk2 <= 2048; kk2 <<= 1) {
        for (int j = kk2 >> 1; j > 0; j >>= 1) {
            if (j >= 128) {
                skey[PHYS(i0)] = k0; skey[PHYS(i1)] = k1;
                __syncthreads();
                u64 o0 = skey[PHYS(i0 ^ j)], o1 = skey[PHYS(i1 ^ j)];
                __syncthreads();
                k0 = bsel(k0, o0, i0, kk2, j);
                k1 = bsel(k1, o1, i1, kk2, j);
            } else if (j >= 2) {
                u64 o0 = __shfl_xor(k0, j >> 1, 64);
                u64 o1 = __shfl_xor(k1, j >> 1, 64);
                k0 = bsel(k0, o0, i0, kk2, j);
                k1 = bsel(k1, o1, i1, kk2, j);
            } else {
                bool mx0 = ((i0 & kk2) == 0);
                u64 mx = umx(k0, k1), mn = umn(k0, k1);
                k0 = mx0 ? mx : mn; k1 = mx0 ? mn : mx;
            }
        }
    }
    skey[PHYS(i0)] = k0; skey[PHYS(i1)] = k1;   // last cross-wave read was pre-barrier
    __syncthreads();

    if (tid < 600) {
        int r = tid / 6, f = tid - (tid / 6) * 6;
        u64 kk = skey[PHYS(r)];
        float v = 0.f;
        if ((unsigned)(kk >> 32) != 0u) {
            int e = (int)(0xFFFFFFFFu - (unsigned)kk) - 100;
            int ci = e / 100, pos = e - ci * 100;
            v = base[ci * 600 + pos * 6 + f];
        }
        out[(size_t)n * 600 + tid] = v;
    }
}

extern "C" void kernel_launch(void* const* d_in, const int* in_sizes, int n_in,
                              void* d_out, int out_size, void* d_ws, size_t ws_size,
                              hipStream_t stream) {
    const float* cls = (const float*)d_in[0];   // [8,16384,21]
    const float* reg = (const float*)d_in[1];   // [8,16384,4]
    const float* anc = (const float*)d_in[2];   // [16384,4]
    float* out = (float*)d_out;                 // [8,100,6]

    // ws layout (floats): boxes 524288 | scores 2621440 | rows 96000
    float* boxes  = (float*)d_ws;
    float* scores = boxes + (size_t)N_IMG * A * 4;
    float* rows   = scores + (size_t)N_IMG * NC * A;

    preprocess_kernel<<<(N_IMG * A) / 256, 256, 0, stream>>>(cls, reg, anc, (float4*)boxes, scores);
    nms_kernel<<<N_IMG * NC, TN, 0, stream>>>((const float4*)boxes, scores, rows);
    topk_kernel<<<N_IMG, 1024, 0, stream>>>(rows, out);
}

// Round 7
// 150.351 us; speedup vs baseline: 1.1944x; 1.0286x over previous
//
#include <hip/hip_runtime.h>

// Detection post-process: softmax -> decode -> per-class LAZY NMS -> top-100.
// N=8 images, A=16384 anchors, C=21 classes (class 0 = background).
//
// Budget model (R8-R12 counters): ~41us harness ws-fill (fixed) + preprocess + nms
// + topk + gaps ~= 83.5us fixed beyond nms. R7 nms = 60.4us @ TN=512.
// Measured TN scan: 256->121.6, 512->60.4, 1024->70.0 => TN=512 optimal; body is
// latency/serial-bound (not width-bound). Single-chunk pipeline ~17-20us but the
// dispatch = max over blocks => slow blocks do 2-4 REFILLS (pops-to-100-accepts ~
// (e^(100p)-1)/p blows past TARGET=384 for p~0.03).
// R13: CAPC 512->1024, TARGET 384->896 (one chunk covers ~900 pops: refills gone
// for ~all blocks; sort-1024 = 2 keys/thread, the topk_kernel-verified network) +
// bijective XCD swizzle so an image's 20 blocks share one XCD L2 for boxes.
// R10 lesson: no in-kernel cross-block coherence (buffer_wbl2/inv cost) -- topk
// stays a separate dispatch. R11 lesson: no kill-matrix (T^2/2 IoUs >> lazy walk).
// Exactness invariants (absmax 0.0 since R1):
//   - u64 key = (score_bits<<32)|~idx  => exact (score desc, idx asc) total order
//   - monotone bin(float bits) => bin-threshold selection is a key-order cut;
//     chunk size/target does NOT change the accept sequence
//   - lazy NMS: dead entries never kill => test pops against accepted set only
//   - division-free EXACT IoU predicate:
//     RN_f32(inter/un) > 0.45f  <=>  (double)inter > ((double)0.45f + 2^-26)*(double)un
//   - topk key = (score_bits<<32)|(0xFFFFFFFF-(flat_j+100)) => exact lax.top_k order

typedef unsigned long long u64;

#define N_IMG 8
#define A     16384
#define NCLS  21
#define NC    20
#define TOPK  100
#define PROB_THR 0.05f

#define TN     512         // nms threads (8 waves, 2/SIMD). Measured optimum (R9/R12).
#define NSLOT  32          // scores per thread
#define NBIN   1152        // score-bit bins: (bits>>15)-31385 spans (0.05,1]
#define BINOFF 31385
#define CAPC   1024        // chunk capacity (sorted); covers ~900 pops -> no refills
#define TARGET 896

#define PHYS(i) ((i) + ((i) >> 4))   // LDS u64 swizzle: breaks power-of-2 strides

#define MIDTHR ((double)0.45f + 0x1p-26)

#define AIDX(t_) ((tid << 2) + (((t_) >> 2) << 11) + ((t_) & 3))

__device__ __forceinline__ u64 pk(float v, int i) {
    return (v > 0.f) ? (((u64)__float_as_uint(v) << 32) | (u64)(unsigned)(~(unsigned)i)) : 0ull;
}
__device__ __forceinline__ float upv(u64 k) { return __uint_as_float((unsigned)(k >> 32)); }
__device__ __forceinline__ int   upi(u64 k) { return (int)(~(unsigned)k); }
__device__ __forceinline__ u64 umx(u64 a, u64 b) { return a > b ? a : b; }
__device__ __forceinline__ u64 umn(u64 a, u64 b) { return a < b ? a : b; }

// bitonic compare-exchange keep-rule for element i at stage (k,j):
// region (i&k)==0 sorts descending; lower partner ((i&j)==0) keeps max there.
__device__ __forceinline__ u64 bsel(u64 mine, u64 other, int i, int k, int j) {
    bool keep_max = ((i & k) == 0) == ((i & j) == 0);
    return keep_max ? umx(mine, other) : umn(mine, other);
}

__device__ __forceinline__ int binOf(float s) {
    int b = (int)(__float_as_uint(s) >> 15) - BINOFF;
    return b < 0 ? 0 : (b > NBIN - 1 ? NBIN - 1 : b);
}

// exact ref predicate: RN(inter/union) > 0.45f
__device__ __forceinline__ bool killp(float4 b, float ab, float4 s, float as_) {
    float lx = fmaxf(s.x, b.x), ly = fmaxf(s.y, b.y);
    float rx = fminf(s.z, b.z), ry = fminf(s.w, b.w);
    float iw = fmaxf(rx - lx, 0.f), ih = fmaxf(ry - ly, 0.f);
    float inter = iw * ih;
    float un = as_ + ab - inter;
    return (double)inter > MIDTHR * (double)un;
}

// Kernel 1: softmax + threshold -> scores[N][NC][A]; SSD decode -> clamped corner boxes.
__global__ __launch_bounds__(256) void preprocess_kernel(
    const float* __restrict__ cls, const float* __restrict__ reg,
    const float* __restrict__ anc, float4* __restrict__ boxes,
    float* __restrict__ scores) {
    __shared__ __align__(16) float lcls[256 * NCLS];
    const int tid = threadIdx.x;
    const int t = blockIdx.x * 256 + tid;

    const float4* src = (const float4*)(cls + (size_t)blockIdx.x * (256 * NCLS));
    float4* dst = (float4*)lcls;
    for (int i = tid; i < (256 * NCLS) / 4; i += 256) dst[i] = src[i];
    __syncthreads();

    const int n = t >> 14;
    const int a = t & (A - 1);
    const float* c = lcls + tid * NCLS;
    float z[NCLS];
    float m = -1e30f;
#pragma unroll
    for (int k = 0; k < NCLS; ++k) { z[k] = c[k]; m = fmaxf(m, z[k]); }
    float s = 0.f;
#pragma unroll
    for (int k = 0; k < NCLS; ++k) { z[k] = expf(z[k] - m); s += z[k]; }
    const float inv = 1.f / s;
#pragma unroll
    for (int k = 0; k < NC; ++k) {
        float p = z[k + 1] * inv;
        scores[(((size_t)n * NC + k) << 14) + a] = (p > PROB_THR) ? p : -1.f;
    }

    const float4 l4 = ((const float4*)reg)[t];
    const float4 an = ((const float4*)anc)[a];
    const float cx = an.x + l4.x * 0.1f * an.z;
    const float cy = an.y + l4.y * 0.1f * an.w;
    const float w  = an.z * expf(l4.z * 0.2f);
    const float h  = an.w * expf(l4.w * 0.2f);
    float x0 = fminf(fmaxf(cx - 0.5f * w, 0.f), 1.f);
    float y0 = fminf(fmaxf(cy - 0.5f * h, 0.f), 1.f);
    float x1 = fminf(fmaxf(cx + 0.5f * w, 0.f), 1.f);
    float y1 = fminf(fmaxf(cy + 0.5f * h, 0.f), 1.f);
    boxes[t] = make_float4(x0, y0, x1, y1);
}

// Kernel 2: one workgroup per (n, ci). Histogram-select -> sort-1024 -> lazy walk.
__global__ __launch_bounds__(TN) void nms_kernel(
    const float4* __restrict__ boxes, const float* __restrict__ scores,
    float* __restrict__ rows) {
    __shared__ int bins[NBIN];
    __shared__ u64 skey[PHYS(CAPC - 1) + 2];
    __shared__ __align__(16) float4 sbox[CAPC];
    __shared__ u64 red8[TN / 64];
    __shared__ u64 bkey;
    __shared__ __align__(16) float4 bbox;
    __shared__ int sint[3];   // 0:B  1:cnt  2:degenerate

    // bijective XCD swizzle: dispatch d -> block (d%8)*20 + d/8, so the 20 class-
    // blocks of image n land on one XCD (round-robin d%8): shared L2 for boxes[n].
    const int blk = ((int)blockIdx.x % 8) * 20 + (int)blockIdx.x / 8;
    const int n = blk / NC, ci = blk % NC;
    const int tid = threadIdx.x, lane = tid & 63, w = tid >> 6;
    const float* gs = scores + ((size_t)blk << 14);
    const float4* gb = boxes + ((size_t)n << 14);
    float* grows = rows + (size_t)blk * 600;

    // scores -> registers (coalesced float4)
    float sc[NSLOT];
    const float4* gs4 = (const float4*)gs;
#pragma unroll
    for (int k = 0; k < NSLOT / 4; ++k) {
        float4 v = gs4[tid + (k << 9)];
        sc[k * 4 + 0] = v.x; sc[k * 4 + 1] = v.y; sc[k * 4 + 2] = v.z; sc[k * 4 + 3] = v.w;
    }

    float4 accA, accB;
    float arA = 0.f, arB = 0.f;
    int na = 0;
    u64 filter = ~0ull;
    bool done = false;

    while (!done && na < TOPK) {
        // ---- filtered histogram ----
        for (int i = tid; i < NBIN; i += TN) bins[i] = 0;
        if (tid == 0) { sint[1] = 0; sint[2] = 0; }
        __syncthreads();
#pragma unroll
        for (int t = 0; t < NSLOT; ++t) {
            float s = sc[t];
            if (s > 0.f) {
                u64 kk = pk(s, AIDX(t));
                if (kk < filter) atomicAdd(&bins[binOf(s)], 1);
            }
        }
        __syncthreads();

        // ---- select bin threshold B (wave0) ----
        if (tid < 64) {
            int lsum[18];
            int tot = 0;
#pragma unroll
            for (int k = 0; k < 18; ++k) { lsum[k] = bins[tid * 18 + k]; tot += lsum[k]; }
            int pfx = tot;
#pragma unroll
            for (int off = 1; off < 64; off <<= 1) {
                int o = __shfl_up(pfx, off, 64);
                if (lane >= off) pfx += o;
            }
            const int totalAll = __shfl(pfx, 63, 64);
            const int sufAbove = totalAll - pfx;
            const int tgt = totalAll < TARGET ? totalAll : TARGET;
            int run = 0, b1 = -1, b2 = 1 << 30;
#pragma unroll
            for (int k = 17; k >= 0; --k) {
                run += lsum[k];
                int suf = sufAbove + run;
                int b = tid * 18 + k;
                if (suf >= tgt && b > b1) b1 = b;
                if (suf <= CAPC && b < b2) b2 = b;
            }
#pragma unroll
            for (int off = 1; off < 64; off <<= 1) {
                int o1 = __shfl_xor(b1, off, 64); if (o1 > b1) b1 = o1;
                int o2 = __shfl_xor(b2, off, 64); if (o2 < b2) b2 = o2;
            }
            if (lane == 0) {
                sint[0] = b1 > b2 ? b1 : b2;
                sint[2] = (b2 == (1 << 30)) ? 1 : 0;
            }
        }
        __syncthreads();
        const int B = sint[0];
        const int degen = sint[2];

        if (!degen) {
            // ---- compact keys of bins >= B (ballot-aggregated; order fixed by sort) ----
#pragma unroll
            for (int t = 0; t < NSLOT; ++t) {
                float s = sc[t];
                bool pred = false; u64 kk = 0ull;
                if (s > 0.f && binOf(s) >= B) {
                    kk = pk(s, AIDX(t));
                    pred = (kk < filter);
                }
                u64 m = __ballot(pred);
                if (m) {
                    int bse = 0;
                    if (lane == 0) bse = atomicAdd(&sint[1], __popcll(m));
                    bse = __shfl(bse, 0, 64);
                    if (pred) {
                        int sl = bse + __popcll(m & ((1ull << lane) - 1ull));
                        skey[PHYS(sl)] = kk;
                    }
                }
            }
            __syncthreads();
            const int T = sint[1];
            if (T == 0) break;                       // exhausted
            for (int i = T + tid; i < CAPC; i += TN) skey[PHYS(i)] = 0ull;
            __syncthreads();

            // ---- hybrid bitonic sort-1024 desc, 2 keys/thread (topk-verified
            // network): j==1 in-thread, 2<=j<=64 via __shfl_xor(j>>1), j>=128 LDS ----
            {
                const int i0 = tid << 1, i1 = i0 | 1;
                u64 k0 = skey[PHYS(i0)], k1 = skey[PHYS(i1)];
                for (int kk2 = 2; kk2 <= CAPC; kk2 <<= 1) {
                    for (int j = kk2 >> 1; j > 0; j >>= 1) {
                        if (j >= 128) {
                            skey[PHYS(i0)] = k0; skey[PHYS(i1)] = k1;
                            __syncthreads();
                            u64 o0 = skey[PHYS(i0 ^ j)], o1 = skey[PHYS(i1 ^ j)];
                            __syncthreads();
                            k0 = bsel(k0, o0, i0, kk2, j);
                            k1 = bsel(k1, o1, i1, kk2, j);
                        } else if (j >= 2) {
                            u64 o0 = __shfl_xor(k0, j >> 1, 64);
                            u64 o1 = __shfl_xor(k1, j >> 1, 64);
                            k0 = bsel(k0, o0, i0, kk2, j);
                            k1 = bsel(k1, o1, i1, kk2, j);
                        } else {
                            bool mx0 = ((i0 & kk2) == 0);
                            u64 mx = umx(k0, k1), mn = umn(k0, k1);
                            k0 = mx0 ? mx : mn; k1 = mx0 ? mn : mx;
                        }
                    }
                }
                skey[PHYS(i0)] = k0; skey[PHYS(i1)] = k1;  // last cross-read pre-barrier: safe
            }
            __syncthreads();

            // ---- prefetch candidate boxes in sorted order ----
            for (int p = tid; p < CAPC; p += TN) {
                u64 kk = skey[PHYS(p)];
                if (kk) sbox[p] = gb[upi(kk)];
            }
            __syncthreads();

            // ---- lazy walk (all waves redundantly; +1-deep register prefetch) ----
            u64 nk = skey[PHYS(0)];
            float4 nb = sbox[0];
            for (int p = 0; p < T; ++p) {
                u64 kk = nk; float4 cb = nb;
                if (p + 1 < T) { nk = skey[PHYS(p + 1)]; nb = sbox[p + 1]; }
                filter = kk;
                float ca = (cb.z - cb.x) * (cb.w - cb.y);
                bool kill = false;
                if (lane < na)      kill = killp(cb, ca, accA, arA);
                if (lane + 64 < na) kill = kill || killp(cb, ca, accB, arB);
                if (!__any(kill)) {
                    if (tid == 0) {
                        float* o = grows + na * 6;
                        o[0] = cb.x; o[1] = cb.y; o[2] = cb.z; o[3] = cb.w;
                        o[4] = upv(kk); o[5] = (float)(ci + 1);
                    }
                    if (na < 64) { if (lane == na) { accA = cb; arA = ca; } }
                    else if (lane == na - 64) { accB = cb; arB = ca; }
                    ++na;
                    if (na == TOPK) { done = true; break; }
                }
            }
            // next refill's LDS writes are gated by two barriers before any store,
            // so no race with waves still finishing this walk.
        } else {
            // ---- degenerate (one bin > CAPC; never on real data): single extractions ----
            while (na < TOPK) {
                u64 best = 0ull;
#pragma unroll
                for (int t = 0; t < NSLOT; ++t) {
                    float s = sc[t];
                    if (s > 0.f) {
                        u64 kk = pk(s, AIDX(t));
                        if (kk < filter && kk > best) best = kk;
                    }
                }
#pragma unroll
                for (int off = 1; off < 64; off <<= 1) best = umx(best, __shfl_xor(best, off, 64));
                if (lane == 0) red8[w] = best;
                __syncthreads();
                if (tid == 0) {
                    u64 bb = red8[0];
#pragma unroll
                    for (int q = 1; q < TN / 64; ++q) bb = umx(bb, red8[q]);
                    bkey = bb;
                    if (bb) bbox = gb[upi(bb)];
                }
                __syncthreads();
                u64 kk = bkey;
                if (!kk) break;
                filter = kk;
                float4 cb = bbox;
                float ca = (cb.z - cb.x) * (cb.w - cb.y);
                bool kill = false;
                if (lane < na)      kill = killp(cb, ca, accA, arA);
                if (lane + 64 < na) kill = kill || killp(cb, ca, accB, arB);
                if (!__any(kill)) {
                    if (tid == 0) {
                        float* o = grows + na * 6;
                        o[0] = cb.x; o[1] = cb.y; o[2] = cb.z; o[3] = cb.w;
                        o[4] = upv(kk); o[5] = (float)(ci + 1);
                    }
                    if (na < 64) { if (lane == na) { accA = cb; arA = ca; } }
                    else if (lane == na - 64) { accB = cb; arB = ca; }
                    ++na;
                }
                __syncthreads();
            }
            break;
        }
    }
    for (int j = na * 6 + tid; j < 600; j += TN) grows[j] = 0.f;
}

// Kernel 3: per image, bitonic sort of all 2048 padded candidate keys, gather top-100.
// key = (score_bits<<32) | (0xFFFFFFFF - flat_j), flat_j = (ci+1)*100 + pos. Exact
// lax.top_k order; zero-score selections are all-zero rows in both ref and ours.
// Hybrid shuffle/LDS bitonic, 2 keys/thread; only j>=128 via LDS.
__global__ __launch_bounds__(1024) void topk_kernel(
    const float* __restrict__ rows, float* __restrict__ out) {
    __shared__ u64 skey[PHYS(2047) + 2];
    const int n = blockIdx.x, tid = threadIdx.x;
    const float* base = rows + (size_t)n * (NC * 600);
    const int i0 = tid << 1, i1 = i0 | 1;

    u64 k0 = 0ull, k1 = 0ull;
    if (i0 < 2000) {
        int ci = i0 / 100, pos = i0 - ci * 100;
        float s = base[ci * 600 + pos * 6 + 4];
        k0 = ((u64)__float_as_uint(s) << 32) | (u64)(0xFFFFFFFFu - (unsigned)(i0 + 100));
    }
    if (i1 < 2000) {
        int ci = i1 / 100, pos = i1 - ci * 100;
        float s = base[ci * 600 + pos * 6 + 4];
        k1 = ((u64)__float_as_uint(s) << 32) | (u64)(0xFFFFFFFFu - (unsigned)(i1 + 100));
    }

    for (int kk2 = 2; kk2 <= 2048; kk2 <<= 1) {
        for (int j = kk2 >> 1; j > 0; j >>= 1) {
            if (j >= 128) {
                skey[PHYS(i0)] = k0; skey[PHYS(i1)] = k1;
                __syncthreads();
                u64 o0 = skey[PHYS(i0 ^ j)], o1 = skey[PHYS(i1 ^ j)];
                __syncthreads();
                k0 = bsel(k0, o0, i0, kk2, j);
                k1 = bsel(k1, o1, i1, kk2, j);
            } else if (j >= 2) {
                u64 o0 = __shfl_xor(k0, j >> 1, 64);
                u64 o1 = __shfl_xor(k1, j >> 1, 64);
                k0 = bsel(k0, o0, i0, kk2, j);
                k1 = bsel(k1, o1, i1, kk2, j);
            } else {
                bool mx0 = ((i0 & kk2) == 0);
                u64 mx = umx(k0, k1), mn = umn(k0, k1);
                k0 = mx0 ? mx : mn; k1 = mx0 ? mn : mx;
            }
        }
    }
    skey[PHYS(i0)] = k0; skey[PHYS(i1)] = k1;   // last cross-wave read was pre-barrier
    __syncthreads();

    if (tid < 600) {
        int r = tid / 6, f = tid - (tid / 6) * 6;
        u64 kk = skey[PHYS(r)];
        float v = 0.f;
        if ((unsigned)(kk >> 32) != 0u) {
            int e = (int)(0xFFFFFFFFu - (unsigned)kk) - 100;
            int ci = e / 100, pos = e - ci * 100;
            v = base[ci * 600 + pos * 6 + f];
        }
        out[(size_t)n * 600 + tid] = v;
    }
}

extern "C" void kernel_launch(void* const* d_in, const int* in_sizes, int n_in,
                              void* d_out, int out_size, void* d_ws, size_t ws_size,
                              hipStream_t stream) {
    const float* cls = (const float*)d_in[0];   // [8,16384,21]
    const float* reg = (const float*)d_in[1];   // [8,16384,4]
    const float* anc = (const float*)d_in[2];   // [16384,4]
    float* out = (float*)d_out;                 // [8,100,6]

    // ws layout (floats): boxes 524288 | scores 2621440 | rows 96000
    float* boxes  = (float*)d_ws;
    float* scores = boxes + (size_t)N_IMG * A * 4;
    float* rows   = scores + (size_t)N_IMG * NC * A;

    preprocess_kernel<<<(N_IMG * A) / 256, 256, 0, stream>>>(cls, reg, anc, (float4*)boxes, scores);
    nms_kernel<<<N_IMG * NC, TN, 0, stream>>>((const float4*)boxes, scores, rows);
    topk_kernel<<<N_IMG, 1024, 0, stream>>>(rows, out);
}

// Round 8
// 145.326 us; speedup vs baseline: 1.2357x; 1.0346x over previous
//
#include <hip/hip_runtime.h>

// Detection post-process: softmax -> decode -> per-class LAZY NMS -> top-100.
// N=8 images, A=16384 anchors, C=21 classes (class 0 = background).
//
// Measurement ledger (nms dispatch, hw timestamps):
//   TN=512 CAPC=512  (R7):  60.4us  <- best; this file's base
//   TN=256 CAPC=512  (R9):  121.6us (1 wave/SIMD: latency exposed)
//   TN=1024 CAPC=512 (R12): 70.0us  (redundant-walk waves + barrier cost)
//   TN=512 CAPC=1024 (R13): 80.3us  (sort/gather scale with CAPC: +20us)
//   kill-matrix      (R11): 96.2us  (T^2/2 IoUs >> lazy walk)
//   in-kernel topk   (R10): 83.1us  (__threadfence => buffer_wbl2/inv L2 flush)
// Fixed budget outside nms: ~41us harness ws-fill + ~12 preprocess + topk + gaps.
// Working decomposition of the 60us (closes at ~1.3-1.5GHz low-util clock):
//   load/hist/select/compact ~15-20us, sort-512 ~10-12us, walk ~15-25us.
// R14: R7 body EXACT except two free walk optimizations: sarea precomputed at
// gather (saves 3 VALU/pop/wave) and depth-2 register prefetch (covers the
// ~120cy LDS round-trip per pop). No swizzle, no geometry change -> clean A/B
// against R7's 60.4.
// Exactness invariants (absmax 0.0 since R1):
//   - u64 key = (score_bits<<32)|~idx  => exact (score desc, idx asc) total order
//   - monotone bin(float bits) => bin-threshold selection is a key-order cut
//   - lazy NMS: dead entries never kill => test pops against accepted set only
//   - division-free EXACT IoU predicate:
//     RN_f32(inter/un) > 0.45f  <=>  (double)inter > ((double)0.45f + 2^-26)*(double)un
//   - topk key = (score_bits<<32)|(0xFFFFFFFF-(flat_j+100)) => exact lax.top_k order

typedef unsigned long long u64;

#define N_IMG 8
#define A     16384
#define NCLS  21
#define NC    20
#define TOPK  100
#define PROB_THR 0.05f

#define TN     512         // 8 waves, 2/SIMD — measured optimum (R9/R12)
#define NSLOT  32          // scores per thread
#define NBIN   1152        // score-bit bins: (bits>>15)-31385 spans (0.05,1]
#define BINOFF 31385
#define CAPC   512         // chunk capacity — measured optimum (R13)
#define TARGET 384

#define PHYS(i) ((i) + ((i) >> 4))   // LDS u64 swizzle: breaks power-of-2 strides

#define MIDTHR ((double)0.45f + 0x1p-26)

#define AIDX(t_) ((tid << 2) + (((t_) >> 2) << 11) + ((t_) & 3))

__device__ __forceinline__ u64 pk(float v, int i) {
    return (v > 0.f) ? (((u64)__float_as_uint(v) << 32) | (u64)(unsigned)(~(unsigned)i)) : 0ull;
}
__device__ __forceinline__ float upv(u64 k) { return __uint_as_float((unsigned)(k >> 32)); }
__device__ __forceinline__ int   upi(u64 k) { return (int)(~(unsigned)k); }
__device__ __forceinline__ u64 umx(u64 a, u64 b) { return a > b ? a : b; }
__device__ __forceinline__ u64 umn(u64 a, u64 b) { return a < b ? a : b; }

// bitonic compare-exchange keep-rule for element i at stage (k,j):
// region (i&k)==0 sorts descending; lower partner ((i&j)==0) keeps max there.
__device__ __forceinline__ u64 bsel(u64 mine, u64 other, int i, int k, int j) {
    bool keep_max = ((i & k) == 0) == ((i & j) == 0);
    return keep_max ? umx(mine, other) : umn(mine, other);
}

__device__ __forceinline__ int binOf(float s) {
    int b = (int)(__float_as_uint(s) >> 15) - BINOFF;
    return b < 0 ? 0 : (b > NBIN - 1 ? NBIN - 1 : b);
}

// exact ref predicate: RN(inter/union) > 0.45f
__device__ __forceinline__ bool killp(float4 b, float ab, float4 s, float as_) {
    float lx = fmaxf(s.x, b.x), ly = fmaxf(s.y, b.y);
    float rx = fminf(s.z, b.z), ry = fminf(s.w, b.w);
    float iw = fmaxf(rx - lx, 0.f), ih = fmaxf(ry - ly, 0.f);
    float inter = iw * ih;
    float un = as_ + ab - inter;
    return (double)inter > MIDTHR * (double)un;
}

// Kernel 1: softmax + threshold -> scores[N][NC][A]; SSD decode -> clamped corner boxes.
__global__ __launch_bounds__(256) void preprocess_kernel(
    const float* __restrict__ cls, const float* __restrict__ reg,
    const float* __restrict__ anc, float4* __restrict__ boxes,
    float* __restrict__ scores) {
    __shared__ __align__(16) float lcls[256 * NCLS];
    const int tid = threadIdx.x;
    const int t = blockIdx.x * 256 + tid;

    const float4* src = (const float4*)(cls + (size_t)blockIdx.x * (256 * NCLS));
    float4* dst = (float4*)lcls;
    for (int i = tid; i < (256 * NCLS) / 4; i += 256) dst[i] = src[i];
    __syncthreads();

    const int n = t >> 14;
    const int a = t & (A - 1);
    const float* c = lcls + tid * NCLS;
    float z[NCLS];
    float m = -1e30f;
#pragma unroll
    for (int k = 0; k < NCLS; ++k) { z[k] = c[k]; m = fmaxf(m, z[k]); }
    float s = 0.f;
#pragma unroll
    for (int k = 0; k < NCLS; ++k) { z[k] = expf(z[k] - m); s += z[k]; }
    const float inv = 1.f / s;
#pragma unroll
    for (int k = 0; k < NC; ++k) {
        float p = z[k + 1] * inv;
        scores[(((size_t)n * NC + k) << 14) + a] = (p > PROB_THR) ? p : -1.f;
    }

    const float4 l4 = ((const float4*)reg)[t];
    const float4 an = ((const float4*)anc)[a];
    const float cx = an.x + l4.x * 0.1f * an.z;
    const float cy = an.y + l4.y * 0.1f * an.w;
    const float w  = an.z * expf(l4.z * 0.2f);
    const float h  = an.w * expf(l4.w * 0.2f);
    float x0 = fminf(fmaxf(cx - 0.5f * w, 0.f), 1.f);
    float y0 = fminf(fmaxf(cy - 0.5f * h, 0.f), 1.f);
    float x1 = fminf(fmaxf(cx + 0.5f * w, 0.f), 1.f);
    float y1 = fminf(fmaxf(cy + 0.5f * h, 0.f), 1.f);
    boxes[t] = make_float4(x0, y0, x1, y1);
}

// Kernel 2: one workgroup per (n, ci). Histogram-select -> sort-512 -> lazy walk.
__global__ __launch_bounds__(TN) void nms_kernel(
    const float4* __restrict__ boxes, const float* __restrict__ scores,
    float* __restrict__ rows) {
    __shared__ int bins[NBIN];
    __shared__ u64 skey[PHYS(CAPC - 1) + 2];
    __shared__ __align__(16) float4 sbox[CAPC];
    __shared__ float sarea[CAPC];
    __shared__ u64 red8[TN / 64];
    __shared__ u64 bkey;
    __shared__ __align__(16) float4 bbox;
    __shared__ int sint[3];   // 0:B  1:cnt  2:degenerate

    const int blk = blockIdx.x, n = blk / NC, ci = blk % NC;
    const int tid = threadIdx.x, lane = tid & 63, w = tid >> 6;
    const float* gs = scores + ((size_t)blk << 14);
    const float4* gb = boxes + ((size_t)n << 14);
    float* grows = rows + (size_t)blk * 600;

    // scores -> registers (coalesced float4)
    float sc[NSLOT];
    const float4* gs4 = (const float4*)gs;
#pragma unroll
    for (int k = 0; k < NSLOT / 4; ++k) {
        float4 v = gs4[tid + (k << 9)];
        sc[k * 4 + 0] = v.x; sc[k * 4 + 1] = v.y; sc[k * 4 + 2] = v.z; sc[k * 4 + 3] = v.w;
    }

    float4 accA, accB;
    float arA = 0.f, arB = 0.f;
    int na = 0;
    u64 filter = ~0ull;
    bool done = false;

    while (!done && na < TOPK) {
        // ---- filtered histogram ----
        for (int i = tid; i < NBIN; i += TN) bins[i] = 0;
        if (tid == 0) { sint[1] = 0; sint[2] = 0; }
        __syncthreads();
#pragma unroll
        for (int t = 0; t < NSLOT; ++t) {
            float s = sc[t];
            if (s > 0.f) {
                u64 kk = pk(s, AIDX(t));
                if (kk < filter) atomicAdd(&bins[binOf(s)], 1);
            }
        }
        __syncthreads();

        // ---- select bin threshold B (wave0) ----
        if (tid < 64) {
            int lsum[18];
            int tot = 0;
#pragma unroll
            for (int k = 0; k < 18; ++k) { lsum[k] = bins[tid * 18 + k]; tot += lsum[k]; }
            int pfx = tot;
#pragma unroll
            for (int off = 1; off < 64; off <<= 1) {
                int o = __shfl_up(pfx, off, 64);
                if (lane >= off) pfx += o;
            }
            const int totalAll = __shfl(pfx, 63, 64);
            const int sufAbove = totalAll - pfx;
            const int tgt = totalAll < TARGET ? totalAll : TARGET;
            int run = 0, b1 = -1, b2 = 1 << 30;
#pragma unroll
            for (int k = 17; k >= 0; --k) {
                run += lsum[k];
                int suf = sufAbove + run;
                int b = tid * 18 + k;
                if (suf >= tgt && b > b1) b1 = b;
                if (suf <= CAPC && b < b2) b2 = b;
            }
#pragma unroll
            for (int off = 1; off < 64; off <<= 1) {
                int o1 = __shfl_xor(b1, off, 64); if (o1 > b1) b1 = o1;
                int o2 = __shfl_xor(b2, off, 64); if (o2 < b2) b2 = o2;
            }
            if (lane == 0) {
                sint[0] = b1 > b2 ? b1 : b2;
                sint[2] = (b2 == (1 << 30)) ? 1 : 0;
            }
        }
        __syncthreads();
        const int B = sint[0];
        const int degen = sint[2];

        if (!degen) {
            // ---- compact keys of bins >= B (ballot-aggregated; order fixed by sort) ----
#pragma unroll
            for (int t = 0; t < NSLOT; ++t) {
                float s = sc[t];
                bool pred = false; u64 kk = 0ull;
                if (s > 0.f && binOf(s) >= B) {
                    kk = pk(s, AIDX(t));
                    pred = (kk < filter);
                }
                u64 m = __ballot(pred);
                if (m) {
                    int bse = 0;
                    if (lane == 0) bse = atomicAdd(&sint[1], __popcll(m));
                    bse = __shfl(bse, 0, 64);
                    if (pred) {
                        int sl = bse + __popcll(m & ((1ull << lane) - 1ull));
                        skey[PHYS(sl)] = kk;
                    }
                }
            }
            __syncthreads();
            const int T = sint[1];
            if (T == 0) break;                       // exhausted
            for (int i = T + tid; i < CAPC; i += TN) skey[PHYS(i)] = 0ull;
            __syncthreads();

            // ---- hybrid bitonic sort 512 u64 desc: __shfl_xor j<=32, LDS j>=64 ----
            {
                u64 myk = skey[PHYS(tid)];
                for (int kk2 = 2; kk2 <= CAPC; kk2 <<= 1) {
                    for (int j = kk2 >> 1; j > 0; j >>= 1) {
                        u64 other;
                        if (j >= 64) {
                            skey[PHYS(tid)] = myk;
                            __syncthreads();
                            other = skey[PHYS(tid ^ j)];
                            __syncthreads();
                        } else {
                            other = __shfl_xor(myk, j, 64);
                        }
                        myk = bsel(myk, other, tid, kk2, j);
                    }
                }
                skey[PHYS(tid)] = myk;   // last cross-wave read was pre-barrier: safe
            }
            __syncthreads();

            // ---- prefetch candidate boxes + areas in sorted order ----
            for (int p = tid; p < CAPC; p += TN) {
                u64 kk = skey[PHYS(p)];
                if (kk) {
                    float4 b = gb[upi(kk)];
                    sbox[p] = b;
                    sarea[p] = (b.z - b.x) * (b.w - b.y);
                }
            }
            __syncthreads();

            // ---- lazy walk (all waves redundantly; depth-2 register prefetch) ----
            u64 pk0 = skey[PHYS(0)], pk1 = 0ull;
            float4 pb0 = sbox[0], pb1 = pb0;
            float pa0 = sarea[0], pa1 = 0.f;
            if (T > 1) { pk1 = skey[PHYS(1)]; pb1 = sbox[1]; pa1 = sarea[1]; }
            for (int p = 0; p < T; ++p) {
                u64 kk = pk0; float4 cb = pb0; float ca = pa0;
                pk0 = pk1; pb0 = pb1; pa0 = pa1;
                const int p2 = p + 2;
                if (p2 < T) { pk1 = skey[PHYS(p2)]; pb1 = sbox[p2]; pa1 = sarea[p2]; }
                filter = kk;
                bool kill = false;
                if (lane < na)      kill = killp(cb, ca, accA, arA);
                if (lane + 64 < na) kill = kill || killp(cb, ca, accB, arB);
                if (!__any(kill)) {
                    if (tid == 0) {
                        float* o = grows + na * 6;
                        o[0] = cb.x; o[1] = cb.y; o[2] = cb.z; o[3] = cb.w;
                        o[4] = upv(kk); o[5] = (float)(ci + 1);
                    }
                    if (na < 64) { if (lane == na) { accA = cb; arA = ca; } }
                    else if (lane == na - 64) { accB = cb; arB = ca; }
                    ++na;
                    if (na == TOPK) { done = true; break; }
                }
            }
            // next refill's skey/sbox/sarea writes are gated by barriers before any
            // store, so no race with waves still finishing this walk.
        } else {
            // ---- degenerate (one bin > CAPC; never on real data): single extractions ----
            while (na < TOPK) {
                u64 best = 0ull;
#pragma unroll
                for (int t = 0; t < NSLOT; ++t) {
                    float s = sc[t];
                    if (s > 0.f) {
                        u64 kk = pk(s, AIDX(t));
                        if (kk < filter && kk > best) best = kk;
                    }
                }
#pragma unroll
                for (int off = 1; off < 64; off <<= 1) best = umx(best, __shfl_xor(best, off, 64));
                if (lane == 0) red8[w] = best;
                __syncthreads();
                if (tid == 0) {
                    u64 bb = red8[0];
#pragma unroll
                    for (int q = 1; q < TN / 64; ++q) bb = umx(bb, red8[q]);
                    bkey = bb;
                    if (bb) bbox = gb[upi(bb)];
                }
                __syncthreads();
                u64 kk = bkey;
                if (!kk) break;
                filter = kk;
                float4 cb = bbox;
                float ca = (cb.z - cb.x) * (cb.w - cb.y);
                bool kill = false;
                if (lane < na)      kill = killp(cb, ca, accA, arA);
                if (lane + 64 < na) kill = kill || killp(cb, ca, accB, arB);
                if (!__any(kill)) {
                    if (tid == 0) {
                        float* o = grows + na * 6;
                        o[0] = cb.x; o[1] = cb.y; o[2] = cb.z; o[3] = cb.w;
                        o[4] = upv(kk); o[5] = (float)(ci + 1);
                    }
                    if (na < 64) { if (lane == na) { accA = cb; arA = ca; } }
                    else if (lane == na - 64) { accB = cb; arB = ca; }
                    ++na;
                }
                __syncthreads();
            }
            break;
        }
    }
    for (int j = na * 6 + tid; j < 600; j += TN) grows[j] = 0.f;
}

// Kernel 3: per image, bitonic sort of all 2048 padded candidate keys, gather top-100.
// key = (score_bits<<32) | (0xFFFFFFFF - flat_j), flat_j = (ci+1)*100 + pos. Exact
// lax.top_k order; zero-score selections are all-zero rows in both ref and ours.
// Hybrid shuffle/LDS bitonic, 2 keys/thread; only j>=128 via LDS.
__global__ __launch_bounds__(1024) void topk_kernel(
    const float* __restrict__ rows, float* __restrict__ out) {
    __shared__ u64 skey[PHYS(2047) + 2];
    const int n = blockIdx.x, tid = threadIdx.x;
    const float* base = rows + (size_t)n * (NC * 600);
    const int i0 = tid << 1, i1 = i0 | 1;

    u64 k0 = 0ull, k1 = 0ull;
    if (i0 < 2000) {
        int ci = i0 / 100, pos = i0 - ci * 100;
        float s = base[ci * 600 + pos * 6 + 4];
        k0 = ((u64)__float_as_uint(s) << 32) | (u64)(0xFFFFFFFFu - (unsigned)(i0 + 100));
    }
    if (i1 < 2000) {
        int ci = i1 / 100, pos = i1 - ci * 100;
        float s = base[ci * 600 + pos * 6 + 4];
        k1 = ((u64)__float_as_uint(s) << 32) | (u64)(0xFFFFFFFFu - (unsigned)(i1 + 100));
    }

    for (int kk2 = 2; kk2 <= 2048; kk2 <<= 1) {
        for (int j = kk2 >> 1; j > 0; j >>= 1) {
            if (j >= 128) {
                skey[PHYS(i0)] = k0; skey[PHYS(i1)] = k1;
                __syncthreads();
                u64 o0 = skey[PHYS(i0 ^ j)], o1 = skey[PHYS(i1 ^ j)];
                __syncthreads();
                k0 = bsel(k0, o0, i0, kk2, j);
                k1 = bsel(k1, o1, i1, kk2, j);
            } else if (j >= 2) {
                u64 o0 = __shfl_xor(k0, j >> 1, 64);
                u64 o1 = __shfl_xor(k1, j >> 1, 64);
                k0 = bsel(k0, o0, i0, kk2, j);
                k1 = bsel(k1, o1, i1, kk2, j);
            } else {
                bool mx0 = ((i0 & kk2) == 0);
                u64 mx = umx(k0, k1), mn = umn(k0, k1);
                k0 = mx0 ? mx : mn; k1 = mx0 ? mn : mx;
            }
        }
    }
    skey[PHYS(i0)] = k0; skey[PHYS(i1)] = k1;   // last cross-wave read was pre-barrier
    __syncthreads();

    if (tid < 600) {
        int r = tid / 6, f = tid - (tid / 6) * 6;
        u64 kk = skey[PHYS(r)];
        float v = 0.f;
        if ((unsigned)(kk >> 32) != 0u) {
            int e = (int)(0xFFFFFFFFu - (unsigned)kk) - 100;
            int ci = e / 100, pos = e - ci * 100;
            v = base[ci * 600 + pos * 6 + f];
        }
        out[(size_t)n * 600 + tid] = v;
    }
}

extern "C" void kernel_launch(void* const* d_in, const int* in_sizes, int n_in,
                              void* d_out, int out_size, void* d_ws, size_t ws_size,
                              hipStream_t stream) {
    const float* cls = (const float*)d_in[0];   // [8,16384,21]
    const float* reg = (const float*)d_in[1];   // [8,16384,4]
    const float* anc = (const float*)d_in[2];   // [16384,4]
    float* out = (float*)d_out;                 // [8,100,6]

    // ws layout (floats): boxes 524288 | scores 2621440 | rows 96000
    float* boxes  = (float*)d_ws;
    float* scores = boxes + (size_t)N_IMG * A * 4;
    float* rows   = scores + (size_t)N_IMG * NC * A;

    preprocess_kernel<<<(N_IMG * A) / 256, 256, 0, stream>>>(cls, reg, anc, (float4*)boxes, scores);
    nms_kernel<<<N_IMG * NC, TN, 0, stream>>>((const float4*)boxes, scores, rows);
    topk_kernel<<<N_IMG, 1024, 0, stream>>>(rows, out);
}

// Round 9
// 114.280 us; speedup vs baseline: 1.5714x; 1.2717x over previous
//
#include <hip/hip_runtime.h>

// Detection post-process: softmax -> decode -> per-class LAZY NMS -> top-100.
// N=8 images, A=16384 anchors, C=21 classes (class 0 = background).
//
// Measurement ledger (nms dispatch, hw timestamps):
//   TN=512 CAPC=512 serial walk (R7/R14): 60.4us  <- base
//   TN=256 (R9): 121.6us | TN=1024 (R12): 70.0us | CAPC=1024 (R13): 80.3us
//   full-512 kill-matrix (R11): 96.2us | in-kernel topk fence (R10): 83.1us
//   walk depth-2 prefetch + sarea (R14): 60.4us (NULL -> walk not LDS-latency-bound)
// Decomposition via TN-scan algebra: phases ~24us, WALK ~30us (serial chain
// ~100cy/pop x ~300 pops), barriers ~5us.
// R15: GROUP-RESOLVE walk: 64-candidate groups, lazily in sorted order.
//   (A) dead-vs-accepted in parallel (8 waves x ballot -> dm[8])
//   (B) group-local 64x64 kill matrix in parallel (gm[8][64], broadcast reads)
//   (D) alive-mask scan, all waves redundant: per ACCEPT cost only
//       (g=ctz(alive); alive &= ~ballot(row>>g & 1)); killed candidates free.
//   (E) popcount-positioned parallel commit to LDS accepted lists.
//   ~2k cy/group x ~5 groups vs ~30us serial walk. R11's scan semantics (passed
//   absmax 0.0) at group granularity; R11's T^2/2-matrix cost avoided.
// Exactness invariants (absmax 0.0 since R1):
//   - u64 key = (score_bits<<32)|~idx  => exact (score desc, idx asc) total order
//   - monotone bin(float bits) => bin-threshold selection is a key-order cut
//   - group scan == lazy NMS: only ACCEPTED candidates kill; order = sorted order;
//     na cap per accept; dead-vs-prev-chunk via accepted list only
//   - division-free EXACT IoU predicate:
//     RN_f32(inter/un) > 0.45f  <=>  (double)inter > ((double)0.45f + 2^-26)*(double)un
//   - topk key = (score_bits<<32)|(0xFFFFFFFF-(flat_j+100)) => exact lax.top_k order

typedef unsigned long long u64;

#define N_IMG 8
#define A     16384
#define NCLS  21
#define NC    20
#define TOPK  100
#define PROB_THR 0.05f

#define TN     512         // 8 waves, 2/SIMD — measured optimum (R9/R12)
#define NSLOT  32          // scores per thread
#define NBIN   1152        // score-bit bins: (bits>>15)-31385 spans (0.05,1]
#define BINOFF 31385
#define CAPC   512         // chunk capacity — measured optimum (R13)
#define TARGET 384

#define PHYS(i) ((i) + ((i) >> 4))   // LDS u64 swizzle: breaks power-of-2 strides

#define MIDTHR ((double)0.45f + 0x1p-26)

#define AIDX(t_) ((tid << 2) + (((t_) >> 2) << 11) + ((t_) & 3))

__device__ __forceinline__ u64 pk(float v, int i) {
    return (v > 0.f) ? (((u64)__float_as_uint(v) << 32) | (u64)(unsigned)(~(unsigned)i)) : 0ull;
}
__device__ __forceinline__ float upv(u64 k) { return __uint_as_float((unsigned)(k >> 32)); }
__device__ __forceinline__ int   upi(u64 k) { return (int)(~(unsigned)k); }
__device__ __forceinline__ u64 umx(u64 a, u64 b) { return a > b ? a : b; }
__device__ __forceinline__ u64 umn(u64 a, u64 b) { return a < b ? a : b; }

// bitonic compare-exchange keep-rule for element i at stage (k,j):
// region (i&k)==0 sorts descending; lower partner ((i&j)==0) keeps max there.
__device__ __forceinline__ u64 bsel(u64 mine, u64 other, int i, int k, int j) {
    bool keep_max = ((i & k) == 0) == ((i & j) == 0);
    return keep_max ? umx(mine, other) : umn(mine, other);
}

__device__ __forceinline__ int binOf(float s) {
    int b = (int)(__float_as_uint(s) >> 15) - BINOFF;
    return b < 0 ? 0 : (b > NBIN - 1 ? NBIN - 1 : b);
}

// exact ref predicate: RN(inter/union) > 0.45f
__device__ __forceinline__ bool killp(float4 b, float ab, float4 s, float as_) {
    float lx = fmaxf(s.x, b.x), ly = fmaxf(s.y, b.y);
    float rx = fminf(s.z, b.z), ry = fminf(s.w, b.w);
    float iw = fmaxf(rx - lx, 0.f), ih = fmaxf(ry - ly, 0.f);
    float inter = iw * ih;
    float un = as_ + ab - inter;
    return (double)inter > MIDTHR * (double)un;
}

// Kernel 1: softmax + threshold -> scores[N][NC][A]; SSD decode -> clamped corner boxes.
__global__ __launch_bounds__(256) void preprocess_kernel(
    const float* __restrict__ cls, const float* __restrict__ reg,
    const float* __restrict__ anc, float4* __restrict__ boxes,
    float* __restrict__ scores) {
    __shared__ __align__(16) float lcls[256 * NCLS];
    const int tid = threadIdx.x;
    const int t = blockIdx.x * 256 + tid;

    const float4* src = (const float4*)(cls + (size_t)blockIdx.x * (256 * NCLS));
    float4* dst = (float4*)lcls;
    for (int i = tid; i < (256 * NCLS) / 4; i += 256) dst[i] = src[i];
    __syncthreads();

    const int n = t >> 14;
    const int a = t & (A - 1);
    const float* c = lcls + tid * NCLS;
    float z[NCLS];
    float m = -1e30f;
#pragma unroll
    for (int k = 0; k < NCLS; ++k) { z[k] = c[k]; m = fmaxf(m, z[k]); }
    float s = 0.f;
#pragma unroll
    for (int k = 0; k < NCLS; ++k) { z[k] = expf(z[k] - m); s += z[k]; }
    const float inv = 1.f / s;
#pragma unroll
    for (int k = 0; k < NC; ++k) {
        float p = z[k + 1] * inv;
        scores[(((size_t)n * NC + k) << 14) + a] = (p > PROB_THR) ? p : -1.f;
    }

    const float4 l4 = ((const float4*)reg)[t];
    const float4 an = ((const float4*)anc)[a];
    const float cx = an.x + l4.x * 0.1f * an.z;
    const float cy = an.y + l4.y * 0.1f * an.w;
    const float w  = an.z * expf(l4.z * 0.2f);
    const float h  = an.w * expf(l4.w * 0.2f);
    float x0 = fminf(fmaxf(cx - 0.5f * w, 0.f), 1.f);
    float y0 = fminf(fmaxf(cy - 0.5f * h, 0.f), 1.f);
    float x1 = fminf(fmaxf(cx + 0.5f * w, 0.f), 1.f);
    float y1 = fminf(fmaxf(cy + 0.5f * h, 0.f), 1.f);
    boxes[t] = make_float4(x0, y0, x1, y1);
}

// Kernel 2: one workgroup per (n, ci). hist-select -> sort-512 -> group-resolve.
__global__ __launch_bounds__(TN) void nms_kernel(
    const float4* __restrict__ boxes, const float* __restrict__ scores,
    float* __restrict__ rows) {
    __shared__ int bins[NBIN];
    __shared__ u64 skey[PHYS(CAPC - 1) + 2];
    __shared__ __align__(16) float4 sbox[CAPC];
    __shared__ float sarea[CAPC];
    __shared__ u64 gm[8][64];          // group kill-matrix partials
    __shared__ u64 dm[8];              // group dead-vs-accepted partials
    __shared__ __align__(16) float4 abox[TOPK];   // accepted list
    __shared__ float aarea[TOPK];
    __shared__ u64 akey[TOPK];
    __shared__ u64 red8[TN / 64];
    __shared__ u64 bkey;
    __shared__ __align__(16) float4 bbox;
    __shared__ int sint[3];   // 0:B  1:cnt  2:degenerate

    const int blk = blockIdx.x, n = blk / NC, ci = blk % NC;
    const int tid = threadIdx.x, lane = tid & 63, w = tid >> 6;
    const float* gs = scores + ((size_t)blk << 14);
    const float4* gb = boxes + ((size_t)n << 14);
    float* grows = rows + (size_t)blk * 600;

    // scores -> registers (coalesced float4)
    float sc[NSLOT];
    const float4* gs4 = (const float4*)gs;
#pragma unroll
    for (int k = 0; k < NSLOT / 4; ++k) {
        float4 v = gs4[tid + (k << 9)];
        sc[k * 4 + 0] = v.x; sc[k * 4 + 1] = v.y; sc[k * 4 + 2] = v.z; sc[k * 4 + 3] = v.w;
    }

    int na = 0;
    u64 filter = ~0ull;
    bool done = false;

    while (!done && na < TOPK) {
        // ---- filtered histogram ----
        for (int i = tid; i < NBIN; i += TN) bins[i] = 0;
        if (tid == 0) { sint[1] = 0; sint[2] = 0; }
        __syncthreads();
#pragma unroll
        for (int t = 0; t < NSLOT; ++t) {
            float s = sc[t];
            if (s > 0.f) {
                u64 kk = pk(s, AIDX(t));
                if (kk < filter) atomicAdd(&bins[binOf(s)], 1);
            }
        }
        __syncthreads();

        // ---- select bin threshold B (wave0) ----
        if (tid < 64) {
            int lsum[18];
            int tot = 0;
#pragma unroll
            for (int k = 0; k < 18; ++k) { lsum[k] = bins[tid * 18 + k]; tot += lsum[k]; }
            int pfx = tot;
#pragma unroll
            for (int off = 1; off < 64; off <<= 1) {
                int o = __shfl_up(pfx, off, 64);
                if (lane >= off) pfx += o;
            }
            const int totalAll = __shfl(pfx, 63, 64);
            const int sufAbove = totalAll - pfx;
            const int tgt = totalAll < TARGET ? totalAll : TARGET;
            int run = 0, b1 = -1, b2 = 1 << 30;
#pragma unroll
            for (int k = 17; k >= 0; --k) {
                run += lsum[k];
                int suf = sufAbove + run;
                int b = tid * 18 + k;
                if (suf >= tgt && b > b1) b1 = b;
                if (suf <= CAPC && b < b2) b2 = b;
            }
#pragma unroll
            for (int off = 1; off < 64; off <<= 1) {
                int o1 = __shfl_xor(b1, off, 64); if (o1 > b1) b1 = o1;
                int o2 = __shfl_xor(b2, off, 64); if (o2 < b2) b2 = o2;
            }
            if (lane == 0) {
                sint[0] = b1 > b2 ? b1 : b2;
                sint[2] = (b2 == (1 << 30)) ? 1 : 0;
            }
        }
        __syncthreads();
        const int B = sint[0];
        const int degen = sint[2];

        if (!degen) {
            // ---- compact keys of bins >= B (ballot-aggregated; order fixed by sort) ----
#pragma unroll
            for (int t = 0; t < NSLOT; ++t) {
                float s = sc[t];
                bool pred = false; u64 kk = 0ull;
                if (s > 0.f && binOf(s) >= B) {
                    kk = pk(s, AIDX(t));
                    pred = (kk < filter);
                }
                u64 m = __ballot(pred);
                if (m) {
                    int bse = 0;
                    if (lane == 0) bse = atomicAdd(&sint[1], __popcll(m));
                    bse = __shfl(bse, 0, 64);
                    if (pred) {
                        int sl = bse + __popcll(m & ((1ull << lane) - 1ull));
                        skey[PHYS(sl)] = kk;
                    }
                }
            }
            __syncthreads();
            const int T = sint[1];
            if (T == 0) break;                       // exhausted
            for (int i = T + tid; i < CAPC; i += TN) skey[PHYS(i)] = 0ull;
            __syncthreads();

            // ---- hybrid bitonic sort 512 u64 desc: __shfl_xor j<=32, LDS j>=64 ----
            {
                u64 myk = skey[PHYS(tid)];
                for (int kk2 = 2; kk2 <= CAPC; kk2 <<= 1) {
                    for (int j = kk2 >> 1; j > 0; j >>= 1) {
                        u64 other;
                        if (j >= 64) {
                            skey[PHYS(tid)] = myk;
                            __syncthreads();
                            other = skey[PHYS(tid ^ j)];
                            __syncthreads();
                        } else {
                            other = __shfl_xor(myk, j, 64);
                        }
                        myk = bsel(myk, other, tid, kk2, j);
                    }
                }
                skey[PHYS(tid)] = myk;   // last cross-wave read was pre-barrier: safe
            }
            __syncthreads();

            // ---- gather candidate boxes + areas in sorted order ----
            for (int p = tid; p < CAPC; p += TN) {
                u64 kk = skey[PHYS(p)];
                if (kk) {
                    float4 b = gb[upi(kk)];
                    sbox[p] = b;
                    sarea[p] = (b.z - b.x) * (b.w - b.y);
                }
            }
            __syncthreads();

            // ---- group-resolve: 64-candidate groups, exact lazy-NMS order ----
            for (int base = 0; base < T && na < TOPK; base += 64) {
                const int cnt = (T - base < 64) ? (T - base) : 64;
                // this lane's candidate (garbage if lane >= cnt: masked below)
                const float4 cb = sbox[base + lane];
                const float ca = sarea[base + lane];
                __syncthreads();   // prev commits / gm readers done before overwrite

                // (A) dead vs previously-accepted: wave w covers q = w, w+8, ...
                bool d = false;
                for (int q = w; q < na; q += 8)
                    d = d || killp(cb, ca, abox[q], aarea[q]);
                u64 dball = __ballot(d);
                if (lane == 0) dm[w] = dball;

                // (B) intra-group matrix: wave w covers j in [8w, 8w+8)
                u64 pr = 0ull;
#pragma unroll
                for (int e = 0; e < 8; ++e) {
                    const int jj = (w << 3) + e;
                    bool kp = (jj < lane) && killp(cb, ca, sbox[base + jj], sarea[base + jj]);
                    pr |= ((u64)kp) << jj;
                }
                gm[w][lane] = pr;
                __syncthreads();

                // (C) OR partials: per-lane row; uniform dead mask
                u64 row = gm[0][lane];
#pragma unroll
                for (int q = 1; q < 8; ++q) row |= gm[q][lane];
                u64 dead = dm[0];
#pragma unroll
                for (int q = 1; q < 8; ++q) dead |= dm[q];

                // (D) alive-mask scan (all waves redundantly; cost ~ #accepts)
                u64 alive = ~dead;
                if (cnt < 64) alive &= (1ull << cnt) - 1ull;
                u64 gacc = 0ull;
                int naL = na;
                while (alive && naL < TOPK) {
                    const int g = (int)__builtin_ctzll(alive);
                    gacc |= 1ull << g;
                    ++naL;
                    const u64 colg = __ballot(((row >> g) & 1ull) != 0ull);
                    alive &= ~colg;
                    alive &= ~(1ull << g);
                }

                // (E) commit accepted (wave0 lanes; position via popcount prefix)
                if (w == 0 && ((gacc >> lane) & 1ull)) {
                    const int pos = na + (int)__popcll(gacc & ((1ull << lane) - 1ull));
                    abox[pos] = cb;
                    aarea[pos] = ca;
                    akey[pos] = skey[PHYS(base + lane)];
                }
                na = naL;   // uniform across block (redundant scan)
            }
            done = (na >= TOPK);
            if (!done) filter = skey[PHYS(T - 1)];   // chunk exhausted: next keys < min
            __syncthreads();                          // commits visible before reuse
        } else {
            // ---- degenerate (one bin > CAPC; never on real data): single extractions ----
            while (na < TOPK) {
                u64 best = 0ull;
#pragma unroll
                for (int t = 0; t < NSLOT; ++t) {
                    float s = sc[t];
                    if (s > 0.f) {
                        u64 kk = pk(s, AIDX(t));
                        if (kk < filter && kk > best) best = kk;
                    }
                }
#pragma unroll
                for (int off = 1; off < 64; off <<= 1) best = umx(best, __shfl_xor(best, off, 64));
                if (lane == 0) red8[w] = best;
                __syncthreads();
                if (tid == 0) {
                    u64 bb = red8[0];
#pragma unroll
                    for (int q = 1; q < TN / 64; ++q) bb = umx(bb, red8[q]);
                    bkey = bb;
                    if (bb) bbox = gb[upi(bb)];
                }
                __syncthreads();
                u64 kk = bkey;
                if (!kk) break;
                filter = kk;
                float4 cb = bbox;
                float ca = (cb.z - cb.x) * (cb.w - cb.y);
                bool kill = false;
                if (lane < na)      kill = killp(cb, ca, abox[lane], aarea[lane]);
                if (lane + 64 < na) kill = kill || killp(cb, ca, abox[lane + 64], aarea[lane + 64]);
                if (!__any(kill)) {
                    if (tid == 0) { abox[na] = cb; aarea[na] = ca; akey[na] = kk; }
                    ++na;           // uniform (all waves same data/math)
                }
                __syncthreads();
            }
            break;
        }
    }

    // ---- final rows write from accepted lists ----
    __syncthreads();
    if (tid < na) {
        float4 b = abox[tid];
        u64 kk = akey[tid];
        float* o = grows + tid * 6;
        o[0] = b.x; o[1] = b.y; o[2] = b.z; o[3] = b.w;
        o[4] = upv(kk); o[5] = (float)(ci + 1);
    }
    for (int j = na * 6 + tid; j < 600; j += TN) grows[j] = 0.f;
}

// Kernel 3: per image, bitonic sort of all 2048 padded candidate keys, gather top-100.
// key = (score_bits<<32) | (0xFFFFFFFF - flat_j), flat_j = (ci+1)*100 + pos. Exact
// lax.top_k order; zero-score selections are all-zero rows in both ref and ours.
// Hybrid shuffle/LDS bitonic, 2 keys/thread; only j>=128 via LDS.
__global__ __launch_bounds__(1024) void topk_kernel(
    const float* __restrict__ rows, float* __restrict__ out) {
    __shared__ u64 skey[PHYS(2047) + 2];
    const int n = blockIdx.x, tid = threadIdx.x;
    const float* base = rows + (size_t)n * (NC * 600);
    const int i0 = tid << 1, i1 = i0 | 1;

    u64 k0 = 0ull, k1 = 0ull;
    if (i0 < 2000) {
        int ci = i0 / 100, pos = i0 - ci * 100;
        float s = base[ci * 600 + pos * 6 + 4];
        k0 = ((u64)__float_as_uint(s) << 32) | (u64)(0xFFFFFFFFu - (unsigned)(i0 + 100));
    }
    if (i1 < 2000) {
        int ci = i1 / 100, pos = i1 - ci * 100;
        float s = base[ci * 600 + pos * 6 + 4];
        k1 = ((u64)__float_as_uint(s) << 32) | (u64)(0xFFFFFFFFu - (unsigned)(i1 + 100));
    }

    for (int kk2 = 2; kk2 <= 2048; kk2 <<= 1) {
        for (int j = kk2 >> 1; j > 0; j >>= 1) {
            if (j >= 128) {
                skey[PHYS(i0)] = k0; skey[PHYS(i1)] = k1;
                __syncthreads();
                u64 o0 = skey[PHYS(i0 ^ j)], o1 = skey[PHYS(i1 ^ j)];
                __syncthreads();
                k0 = bsel(k0, o0, i0, kk2, j);
                k1 = bsel(k1, o1, i1, kk2, j);
            } else if (j >= 2) {
                u64 o0 = __shfl_xor(k0, j >> 1, 64);
                u64 o1 = __shfl_xor(k1, j >> 1, 64);
                k0 = bsel(k0, o0, i0, kk2, j);
                k1 = bsel(k1, o1, i1, kk2, j);
            } else {
                bool mx0 = ((i0 & kk2) == 0);
                u64 mx = umx(k0, k1), mn = umn(k0, k1);
                k0 = mx0 ? mx : mn; k1 = mx0 ? mn : mx;
            }
        }
    }
    skey[PHYS(i0)] = k0; skey[PHYS(i1)] = k1;   // last cross-wave read was pre-barrier
    __syncthreads();

    if (tid < 600) {
        int r = tid / 6, f = tid - (tid / 6) * 6;
        u64 kk = skey[PHYS(r)];
        float v = 0.f;
        if ((unsigned)(kk >> 32) != 0u) {
            int e = (int)(0xFFFFFFFFu - (unsigned)kk) - 100;
            int ci = e / 100, pos = e - ci * 100;
            v = base[ci * 600 + pos * 6 + f];
        }
        out[(size_t)n * 600 + tid] = v;
    }
}

extern "C" void kernel_launch(void* const* d_in, const int* in_sizes, int n_in,
                              void* d_out, int out_size, void* d_ws, size_t ws_size,
                              hipStream_t stream) {
    const float* cls = (const float*)d_in[0];   // [8,16384,21]
    const float* reg = (const float*)d_in[1];   // [8,16384,4]
    const float* anc = (const float*)d_in[2];   // [16384,4]
    float* out = (float*)d_out;                 // [8,100,6]

    // ws layout (floats): boxes 524288 | scores 2621440 | rows 96000
    float* boxes  = (float*)d_ws;
    float* scores = boxes + (size_t)N_IMG * A * 4;
    float* rows   = scores + (size_t)N_IMG * NC * A;

    preprocess_kernel<<<(N_IMG * A) / 256, 256, 0, stream>>>(cls, reg, anc, (float4*)boxes, scores);
    nms_kernel<<<N_IMG * NC, TN, 0, stream>>>((const float4*)boxes, scores, rows);
    topk_kernel<<<N_IMG, 1024, 0, stream>>>(rows, out);
}